// Round 1
// baseline (1811.029 us; speedup 1.0000x reference)
//
#include <hip/hip_runtime.h>
#include <cstdint>

#define DEV __device__ __forceinline__

DEV unsigned short f2bf(float f) {
    unsigned u = __float_as_uint(f);
    unsigned r = u + 0x7fffu + ((u >> 16) & 1u);
    return (unsigned short)(r >> 16);
}
DEV float bcastf(float v, int k) {
    return __uint_as_float(__builtin_amdgcn_readlane((int)__float_as_uint(v), k));
}
DEV float sigm(float x) { return 1.f / (1.f + __expf(-x)); }
DEV float tanh_(float x) {
    x = fminf(fmaxf(x, -15.f), 15.f);
    float e = __expf(2.f * x);
    return (e - 1.f) / (e + 1.f);
}

// ---------------- conv1: (128,3,192,256) -> (128,32,94,126), 5x5 s2, ReLU, bf16 out
__global__ __launch_bounds__(128) void k_conv1(const float* __restrict__ img,
                                               const float* __restrict__ w,
                                               const float* __restrict__ bias,
                                               unsigned short* __restrict__ out) {
    int y = blockIdx.x;   // 0..93
    int b = blockIdx.y;   // 0..127
    int tid = threadIdx.x;
    __shared__ float tile[3 * 1280];  // 3 ch x 5 rows x 256
    for (int u = tid; u < 3 * 1280; u += 128) {
        int c = u / 1280, rem = u % 1280;
        tile[c * 1280 + rem] = img[((b * 3 + c) * 192 + 2 * y) * 256 + rem];
    }
    __syncthreads();
    if (tid < 126) {
        float in_v[75];
#pragma unroll
        for (int c = 0; c < 3; ++c)
#pragma unroll
            for (int r = 0; r < 5; ++r)
#pragma unroll
                for (int kx = 0; kx < 5; ++kx)
                    in_v[c * 25 + r * 5 + kx] = tile[c * 1280 + r * 256 + 2 * tid + kx];
        for (int oc = 0; oc < 32; oc += 2) {
            float a0 = bias[oc], a1 = bias[oc + 1];
#pragma unroll
            for (int j = 0; j < 75; ++j) {
                a0 = fmaf(in_v[j], w[oc * 75 + j], a0);
                a1 = fmaf(in_v[j], w[(oc + 1) * 75 + j], a1);
            }
            out[((b * 32 + oc) * 94 + y) * 126 + tid] = f2bf(fmaxf(a0, 0.f));
            out[((b * 32 + oc + 1) * 94 + y) * 126 + tid] = f2bf(fmaxf(a1, 0.f));
        }
    }
}

// ---------------- conv2: (128,32,94,126) -> (128,64,46,62), 3x3 s2, ReLU, bf16 in/out
__global__ __launch_bounds__(256) void k_conv2(const unsigned short* __restrict__ in,
                                               const float* __restrict__ w,
                                               const float* __restrict__ bias,
                                               unsigned short* __restrict__ out) {
    int y = blockIdx.x;   // 0..45
    int b = blockIdx.y;
    int tid = threadIdx.x;
    int x = tid & 63;       // pixel, <62 active
    int ocg = tid >> 6;     // 0..3, wave-uniform
    __shared__ float tile[32 * 378];  // 32 ch x 3 rows x 126
    const uint32_t* inp = (const uint32_t*)in;
    for (int u = tid; u < 32 * 189; u += 256) {
        int c = u / 189, r2 = u % 189;
        uint32_t v = inp[(((b * 32 + c) * 94 + 2 * y) * 126) / 2 + r2];
        tile[c * 378 + 2 * r2] = __uint_as_float((v & 0xffffu) << 16);
        tile[c * 378 + 2 * r2 + 1] = __uint_as_float(v & 0xffff0000u);
    }
    __syncthreads();
    // wave-uniform weight base -> scalar (SMEM) loads
    const float* wb = w + __builtin_amdgcn_readfirstlane(ocg * 16 * 288);
    float acc[16];
#pragma unroll
    for (int i = 0; i < 16; ++i) acc[i] = bias[ocg * 16 + i];
    if (x < 62) {
        for (int c = 0; c < 32; ++c) {
            float in9[9];
#pragma unroll
            for (int r = 0; r < 3; ++r)
#pragma unroll
                for (int kx = 0; kx < 3; ++kx)
                    in9[r * 3 + kx] = tile[c * 378 + r * 126 + 2 * x + kx];
#pragma unroll
            for (int i = 0; i < 16; ++i)
#pragma unroll
                for (int j = 0; j < 9; ++j)
                    acc[i] = fmaf(in9[j], wb[i * 288 + c * 9 + j], acc[i]);
        }
#pragma unroll
        for (int i = 0; i < 16; ++i)
            out[((b * 64 + ocg * 16 + i) * 46 + y) * 62 + x] = f2bf(fmaxf(acc[i], 0.f));
    }
}

// ---------------- conv3: (128,64,46,62) -> (128,64,22,30), 3x3 s2, no relu, fp32 out (flatten layout)
__global__ __launch_bounds__(256) void k_conv3(const unsigned short* __restrict__ in,
                                               const float* __restrict__ w,
                                               const float* __restrict__ bias,
                                               float* __restrict__ out) {
    int yy = blockIdx.x;   // 0..10 (two output rows per block)
    int b = blockIdx.y;
    int tid = threadIdx.x;
    int p = tid & 63;      // <60 active: 2 rows x 30 px
    int ocg = tid >> 6;    // 0..3, wave-uniform, 16 oc each
    __shared__ float tile[32 * 310];  // half the channels at a time: 32 ch x 5 rows x 62
    const uint32_t* inp = (const uint32_t*)in;
    const float* wb = w + __builtin_amdgcn_readfirstlane(ocg * 16 * 576);
    float acc[16];
#pragma unroll
    for (int i = 0; i < 16; ++i) acc[i] = bias[ocg * 16 + i];
    int ly = p / 30, xx = p % 30;
    for (int cc = 0; cc < 64; cc += 32) {
        __syncthreads();
        for (int u = tid; u < 32 * 155; u += 256) {
            int c = u / 155, r2 = u % 155;
            uint32_t v = inp[(((b * 64 + cc + c) * 46 + 4 * yy) * 62) / 2 + r2];
            tile[c * 310 + 2 * r2] = __uint_as_float((v & 0xffffu) << 16);
            tile[c * 310 + 2 * r2 + 1] = __uint_as_float(v & 0xffff0000u);
        }
        __syncthreads();
        if (p < 60) {
            for (int c = 0; c < 32; ++c) {
                float in9[9];
#pragma unroll
                for (int r = 0; r < 3; ++r)
#pragma unroll
                    for (int kx = 0; kx < 3; ++kx)
                        in9[r * 3 + kx] = tile[c * 310 + (ly * 2 + r) * 62 + 2 * xx + kx];
#pragma unroll
                for (int i = 0; i < 16; ++i)
#pragma unroll
                    for (int j = 0; j < 9; ++j)
                        acc[i] = fmaf(in9[j], wb[i * 576 + (cc + c) * 9 + j], acc[i]);
            }
        }
    }
    if (p < 60) {
        int yo = 2 * yy + ly;
#pragma unroll
        for (int i = 0; i < 16; ++i)
            out[b * 42240 + (ocg * 16 + i) * 660 + yo * 30 + xx] = acc[i];
    }
}

// ---------------- fc1 partials: (128,42240)x(256,42240)^T, K split 4 ways
__global__ __launch_bounds__(256) void k_fc1(const float* __restrict__ x,
                                             const float* __restrict__ w,
                                             float* __restrict__ part) {
    int b = blockIdx.x, kc = blockIdx.y;
    int n = threadIdx.x;
    const float* xr = x + b * 42240 + kc * 10560;
    const float* wr = w + n * 42240 + kc * 10560;
    float a0 = 0.f, a1 = 0.f, a2 = 0.f, a3 = 0.f;
#pragma unroll 2
    for (int k = 0; k < 10560; k += 4) {
        float4 wv = *(const float4*)(wr + k);
        a0 = fmaf(xr[k], wv.x, a0);
        a1 = fmaf(xr[k + 1], wv.y, a1);
        a2 = fmaf(xr[k + 2], wv.z, a2);
        a3 = fmaf(xr[k + 3], wv.w, a3);
    }
    part[(kc * 128 + b) * 256 + n] = (a0 + a1) + (a2 + a3);
}

__global__ __launch_bounds__(256) void k_fc1c(const float* __restrict__ part,
                                              const float* __restrict__ bias,
                                              float* __restrict__ o) {
    int b = blockIdx.x, n = threadIdx.x;
    float s = bias[n];
    for (int kc = 0; kc < 4; ++kc) s += part[(kc * 128 + b) * 256 + n];
    o[b * 256 + n] = fmaxf(s, 0.f);
}

// ---------------- fc2 + lowd1 + lowd2 fused -> cnn_out2 (h0/c0 source)
__global__ __launch_bounds__(128) void k_head(const float* __restrict__ f1o,
                                              const float* __restrict__ w2, const float* __restrict__ b2,
                                              const float* __restrict__ lw1, const float* __restrict__ lb1,
                                              const float* __restrict__ lw2, const float* __restrict__ lb2,
                                              float* __restrict__ cnn2) {
    int b = blockIdx.x, n = threadIdx.x;
    __shared__ float xa[256];
    __shared__ float xb[128];
    __shared__ float xc[128];
    xa[n] = f1o[b * 256 + n];
    xa[n + 128] = f1o[b * 256 + 128 + n];
    __syncthreads();
    float acc = b2[n];
    for (int k = 0; k < 256; ++k) acc = fmaf(xa[k], w2[n * 256 + k], acc);
    xb[n] = acc;  // cnn_out1, no relu
    __syncthreads();
    acc = lb1[n];
    for (int k = 0; k < 128; ++k) acc = fmaf(xb[k], lw1[n * 128 + k], acc);
    xc[n] = fmaxf(acc, 0.f);
    __syncthreads();
    acc = lb2[n];
    for (int k = 0; k < 128; ++k) acc = fmaf(xc[k], lw2[n * 128 + k], acc);
    cnn2[b * 128 + n] = acc;  // [:,:64]=c0, [:,64:]=h0
}

// ---------------- action MLP: (128,8,2) -> (128,8,16)
__global__ __launch_bounds__(256) void k_act(const float* __restrict__ ain,
                                             const float* __restrict__ w1, const float* __restrict__ b1,
                                             const float* __restrict__ w2, const float* __restrict__ b2,
                                             float* __restrict__ abuf) {
    int idx = blockIdx.x * 256 + threadIdx.x;  // b*8+t, 0..1023
    float x0 = ain[idx * 2], x1 = ain[idx * 2 + 1];
    float h1[16];
#pragma unroll
    for (int i = 0; i < 16; ++i)
        h1[i] = fmaxf(fmaf(x0, w1[i * 2], fmaf(x1, w1[i * 2 + 1], b1[i])), 0.f);
#pragma unroll
    for (int i = 0; i < 16; ++i) {
        float a = b2[i];
#pragma unroll
        for (int j = 0; j < 16; ++j) a = fmaf(h1[j], w2[i * 16 + j], a);
        abuf[idx * 16 + i] = a;
    }
}

// ---------------- LSTM: 8 layers x 8 steps, one sample per block, gate = thread,
// weights in VGPRs, x/h broadcast via v_readlane (avoids LDS-broadcast pipe bound)
__global__ __launch_bounds__(256) void k_lstm(const float* __restrict__ abuf,
                                              const float* __restrict__ cnn2,
                                              const float* __restrict__ Wih0,
                                              const float* __restrict__ Wih,
                                              const float* __restrict__ Whh,
                                              const float* __restrict__ bih,
                                              const float* __restrict__ bhh,
                                              float* __restrict__ lout) {
    int b = blockIdx.x, tid = threadIdx.x, lane = tid & 63;
    __shared__ float xs[8][64];
    __shared__ float gbuf[256];
    for (int i = tid; i < 512; i += 256) {
        int t = i >> 6, k = i & 63;
        xs[t][k] = (k < 16) ? abuf[(b * 8 + t) * 16 + k] : 0.f;
    }
    __syncthreads();
    for (int l = 0; l < 8; ++l) {
        float wih[64], whh[64];
        if (l == 0) {
#pragma unroll
            for (int k = 0; k < 64; ++k) wih[k] = (k < 16) ? Wih0[tid * 16 + k] : 0.f;
        } else {
#pragma unroll
            for (int k = 0; k < 64; ++k) wih[k] = Wih[((l - 1) * 256 + tid) * 64 + k];
        }
#pragma unroll
        for (int k = 0; k < 64; ++k) whh[k] = Whh[(l * 256 + tid) * 64 + k];
        float biasv = bih[l * 256 + tid] + bhh[l * 256 + tid];
        // h0/c0 broadcast to every layer
        float v_h = cnn2[b * 128 + 64 + lane];
        float v_c = cnn2[b * 128 + lane];
        for (int t = 0; t < 8; ++t) {
            float v_x = xs[t][lane];
            float a0 = biasv, a1 = 0.f, a2 = 0.f, a3 = 0.f;
#pragma unroll
            for (int k = 0; k < 64; k += 4) {
                a0 = fmaf(wih[k], bcastf(v_x, k), a0);
                a1 = fmaf(wih[k + 1], bcastf(v_x, k + 1), a1);
                a2 = fmaf(wih[k + 2], bcastf(v_x, k + 2), a2);
                a3 = fmaf(wih[k + 3], bcastf(v_x, k + 3), a3);
            }
#pragma unroll
            for (int k = 0; k < 64; k += 4) {
                a0 = fmaf(whh[k], bcastf(v_h, k), a0);
                a1 = fmaf(whh[k + 1], bcastf(v_h, k + 1), a1);
                a2 = fmaf(whh[k + 2], bcastf(v_h, k + 2), a2);
                a3 = fmaf(whh[k + 3], bcastf(v_h, k + 3), a3);
            }
            gbuf[tid] = (a0 + a1) + (a2 + a3);
            __syncthreads();
            // every wave redundantly updates its own h/c copy (lane = state index)
            float gi = gbuf[lane], gf = gbuf[64 + lane], gg = gbuf[128 + lane], go = gbuf[192 + lane];
            float cn = sigm(gf) * v_c + sigm(gi) * tanh_(gg);
            float hn = sigm(go) * tanh_(cn);
            v_c = cn;
            v_h = hn;
            if (tid < 64) xs[t][tid] = hn;  // becomes next layer's input
            __syncthreads();
        }
    }
    for (int i = tid; i < 512; i += 256) {
        int t = i >> 6, k = i & 63;
        lout[(b * 8 + t) * 64 + k] = xs[t][k];
    }
}

// ---------------- out MLP + rotation -> d_out (128,8,4)
__global__ __launch_bounds__(256) void k_out(const float* __restrict__ lout,
                                             const float* __restrict__ w1, const float* __restrict__ b1,
                                             const float* __restrict__ w2, const float* __restrict__ b2,
                                             const float* __restrict__ gt, float* __restrict__ out) {
    int idx = blockIdx.x * 256 + threadIdx.x;  // b*8+t
    int b = idx >> 3;
    float x[64];
#pragma unroll
    for (int j = 0; j < 64; ++j) x[j] = lout[idx * 64 + j];
    float h[32];
#pragma unroll 8
    for (int i = 0; i < 32; ++i) {
        float a = b1[i];
#pragma unroll
        for (int j = 0; j < 64; ++j) a = fmaf(x[j], w1[i * 64 + j], a);
        h[i] = fmaxf(a, 0.f);
    }
    float mo[4];
#pragma unroll
    for (int i = 0; i < 4; ++i) {
        float a = b2[i];
#pragma unroll
        for (int j = 0; j < 32; ++j) a = fmaf(h[j], w2[i * 32 + j], a);
        mo[i] = a;
    }
    float yaw = gt[b * 48 + 5];
    float cy = cosf(yaw), sy = sinf(yaw);
    out[idx * 4 + 0] = fmaf(mo[0], cy, fmaf(mo[1], sy, gt[b * 48 + 1]));
    out[idx * 4 + 1] = fmaf(mo[0], -sy, fmaf(mo[1], cy, gt[b * 48 + 2]));
    out[idx * 4 + 2] = mo[2] + gt[b * 48 + 3];
    out[idx * 4 + 3] = mo[3];
}

extern "C" void kernel_launch(void* const* d_in, const int* in_sizes, int n_in,
                              void* d_out, int out_size, void* d_ws, size_t ws_size,
                              hipStream_t stream) {
    const float* img = (const float*)d_in[0];
    const float* ain = (const float*)d_in[1];
    const float* gt = (const float*)d_in[2];
    const float* c1w = (const float*)d_in[3];
    const float* c1b = (const float*)d_in[4];
    const float* c2w = (const float*)d_in[5];
    const float* c2b = (const float*)d_in[6];
    const float* c3w = (const float*)d_in[7];
    const float* c3b = (const float*)d_in[8];
    const float* f1w = (const float*)d_in[9];
    const float* f1b = (const float*)d_in[10];
    const float* f2w = (const float*)d_in[11];
    const float* f2b = (const float*)d_in[12];
    const float* l1w = (const float*)d_in[13];
    const float* l1b = (const float*)d_in[14];
    const float* l2w = (const float*)d_in[15];
    const float* l2b = (const float*)d_in[16];
    const float* a1w = (const float*)d_in[17];
    const float* a1b = (const float*)d_in[18];
    const float* a2w = (const float*)d_in[19];
    const float* a2b = (const float*)d_in[20];
    const float* wih0 = (const float*)d_in[21];
    const float* wih = (const float*)d_in[22];
    const float* whh = (const float*)d_in[23];
    const float* bihp = (const float*)d_in[24];
    const float* bhhp = (const float*)d_in[25];
    const float* o1w = (const float*)d_in[26];
    const float* o1b = (const float*)d_in[27];
    const float* o2w = (const float*)d_in[28];
    const float* o2b = (const float*)d_in[29];
    float* out = (float*)d_out;

    char* ws = (char*)d_ws;
    unsigned short* c1o = (unsigned short*)(ws);                 // 48,513,024 bf16 = 97,026,048 B
    unsigned short* c2o = (unsigned short*)(ws + 97026048);      // 23,363,584 bf16 = 46,727,168 B
    float* c3o = (float*)(ws + 143753216);                       // 5,406,720 f32
    float* f1p = (float*)(ws + 165380096);                       // 4*128*256
    float* f1o = (float*)(ws + 165904384);                       // 128*256
    float* cnn2 = (float*)(ws + 166035456);                      // 128*128
    float* abuf = (float*)(ws + 166100992);                      // 128*8*16
    float* lo = (float*)(ws + 166166528);                        // 128*8*64

    k_conv1<<<dim3(94, 128), 128, 0, stream>>>(img, c1w, c1b, c1o);
    k_conv2<<<dim3(46, 128), 256, 0, stream>>>(c1o, c2w, c2b, c2o);
    k_conv3<<<dim3(11, 128), 256, 0, stream>>>(c2o, c3w, c3b, c3o);
    k_fc1<<<dim3(128, 4), 256, 0, stream>>>(c3o, f1w, f1p);
    k_fc1c<<<128, 256, 0, stream>>>(f1p, f1b, f1o);
    k_head<<<128, 128, 0, stream>>>(f1o, f2w, f2b, l1w, l1b, l2w, l2b, cnn2);
    k_act<<<4, 256, 0, stream>>>(ain, a1w, a1b, a2w, a2b, abuf);
    k_lstm<<<128, 256, 0, stream>>>(abuf, cnn2, wih0, wih, whh, bihp, bhhp, lo);
    k_out<<<4, 256, 0, stream>>>(lo, o1w, o1b, o2w, o2b, gt, out);
}

// Round 2
// 1070.686 us; speedup vs baseline: 1.6915x; 1.6915x over previous
//
#include <hip/hip_runtime.h>
#include <cstdint>

#define DEV __device__ __forceinline__

typedef __attribute__((ext_vector_type(8))) short bf16x8;
typedef __attribute__((ext_vector_type(4))) float f32x4;

DEV unsigned short f2bf(float f) {
    unsigned u = __float_as_uint(f);
    unsigned r = u + 0x7fffu + ((u >> 16) & 1u);
    return (unsigned short)(r >> 16);
}
DEV float bcastf(float v, int k) {
    return __uint_as_float(__builtin_amdgcn_readlane((int)__float_as_uint(v), k));
}
DEV float sigm(float x) { return 1.f / (1.f + __expf(-x)); }
DEV float tanh_(float x) {
    x = fminf(fmaxf(x, -15.f), 15.f);
    float e = __expf(2.f * x);
    return (e - 1.f) / (e + 1.f);
}

// ---------------- conv1: (128,3,192,256) -> (128,32,94,126), 5x5 s2, ReLU, bf16 out
__global__ __launch_bounds__(128) void k_conv1(const float* __restrict__ img,
                                               const float* __restrict__ w,
                                               const float* __restrict__ bias,
                                               unsigned short* __restrict__ out) {
    int y = blockIdx.x;   // 0..93
    int b = blockIdx.y;   // 0..127
    int tid = threadIdx.x;
    __shared__ float tile[3 * 1280];  // 3 ch x 5 rows x 256
    for (int u = tid; u < 3 * 1280; u += 128) {
        int c = u / 1280, rem = u % 1280;
        tile[c * 1280 + rem] = img[((b * 3 + c) * 192 + 2 * y) * 256 + rem];
    }
    __syncthreads();
    if (tid < 126) {
        float in_v[75];
#pragma unroll
        for (int c = 0; c < 3; ++c)
#pragma unroll
            for (int r = 0; r < 5; ++r)
#pragma unroll
                for (int kx = 0; kx < 5; ++kx)
                    in_v[c * 25 + r * 5 + kx] = tile[c * 1280 + r * 256 + 2 * tid + kx];
        for (int oc = 0; oc < 32; oc += 2) {
            float a0 = bias[oc], a1 = bias[oc + 1];
#pragma unroll
            for (int j = 0; j < 75; ++j) {
                a0 = fmaf(in_v[j], w[oc * 75 + j], a0);
                a1 = fmaf(in_v[j], w[(oc + 1) * 75 + j], a1);
            }
            out[((b * 32 + oc) * 94 + y) * 126 + tid] = f2bf(fmaxf(a0, 0.f));
            out[((b * 32 + oc + 1) * 94 + y) * 126 + tid] = f2bf(fmaxf(a1, 0.f));
        }
    }
}

// ---------------- conv2: (128,32,94,126) -> (128,64,46,62), 3x3 s2, ReLU, bf16 in/out
__global__ __launch_bounds__(256) void k_conv2(const unsigned short* __restrict__ in,
                                               const float* __restrict__ w,
                                               const float* __restrict__ bias,
                                               unsigned short* __restrict__ out) {
    int y = blockIdx.x;   // 0..45
    int b = blockIdx.y;
    int tid = threadIdx.x;
    int x = tid & 63;       // pixel, <62 active
    int ocg = tid >> 6;     // 0..3, wave-uniform
    __shared__ float tile[32 * 378];  // 32 ch x 3 rows x 126
    const uint32_t* inp = (const uint32_t*)in;
    for (int u = tid; u < 32 * 189; u += 256) {
        int c = u / 189, r2 = u % 189;
        uint32_t v = inp[(((b * 32 + c) * 94 + 2 * y) * 126) / 2 + r2];
        tile[c * 378 + 2 * r2] = __uint_as_float((v & 0xffffu) << 16);
        tile[c * 378 + 2 * r2 + 1] = __uint_as_float(v & 0xffff0000u);
    }
    __syncthreads();
    // wave-uniform weight base -> scalar (SMEM) loads
    const float* wb = w + __builtin_amdgcn_readfirstlane(ocg * 16 * 288);
    float acc[16];
#pragma unroll
    for (int i = 0; i < 16; ++i) acc[i] = bias[ocg * 16 + i];
    if (x < 62) {
        for (int c = 0; c < 32; ++c) {
            float in9[9];
#pragma unroll
            for (int r = 0; r < 3; ++r)
#pragma unroll
                for (int kx = 0; kx < 3; ++kx)
                    in9[r * 3 + kx] = tile[c * 378 + r * 126 + 2 * x + kx];
#pragma unroll
            for (int i = 0; i < 16; ++i)
#pragma unroll
                for (int j = 0; j < 9; ++j)
                    acc[i] = fmaf(in9[j], wb[i * 288 + c * 9 + j], acc[i]);
        }
#pragma unroll
        for (int i = 0; i < 16; ++i)
            out[((b * 64 + ocg * 16 + i) * 46 + y) * 62 + x] = f2bf(fmaxf(acc[i], 0.f));
    }
}

// ---------------- conv3: (128,64,46,62) -> (128,64,22,30), 3x3 s2, bf16 out (flatten layout)
__global__ __launch_bounds__(256) void k_conv3(const unsigned short* __restrict__ in,
                                               const float* __restrict__ w,
                                               const float* __restrict__ bias,
                                               unsigned short* __restrict__ out) {
    int yy = blockIdx.x;   // 0..10 (two output rows per block)
    int b = blockIdx.y;
    int tid = threadIdx.x;
    int p = tid & 63;      // <60 active: 2 rows x 30 px
    int ocg = tid >> 6;    // 0..3, wave-uniform, 16 oc each
    __shared__ float tile[32 * 310];  // half the channels at a time: 32 ch x 5 rows x 62
    const uint32_t* inp = (const uint32_t*)in;
    const float* wb = w + __builtin_amdgcn_readfirstlane(ocg * 16 * 576);
    float acc[16];
#pragma unroll
    for (int i = 0; i < 16; ++i) acc[i] = bias[ocg * 16 + i];
    int ly = p / 30, xx = p % 30;
    for (int cc = 0; cc < 64; cc += 32) {
        __syncthreads();
        for (int u = tid; u < 32 * 155; u += 256) {
            int c = u / 155, r2 = u % 155;
            uint32_t v = inp[(((b * 64 + cc + c) * 46 + 4 * yy) * 62) / 2 + r2];
            tile[c * 310 + 2 * r2] = __uint_as_float((v & 0xffffu) << 16);
            tile[c * 310 + 2 * r2 + 1] = __uint_as_float(v & 0xffff0000u);
        }
        __syncthreads();
        if (p < 60) {
            for (int c = 0; c < 32; ++c) {
                float in9[9];
#pragma unroll
                for (int r = 0; r < 3; ++r)
#pragma unroll
                    for (int kx = 0; kx < 3; ++kx)
                        in9[r * 3 + kx] = tile[c * 310 + (ly * 2 + r) * 62 + 2 * xx + kx];
#pragma unroll
                for (int i = 0; i < 16; ++i)
#pragma unroll
                    for (int j = 0; j < 9; ++j)
                        acc[i] = fmaf(in9[j], wb[i * 576 + (cc + c) * 9 + j], acc[i]);
            }
        }
    }
    if (p < 60) {
        int yo = 2 * yy + ly;
#pragma unroll
        for (int i = 0; i < 16; ++i)
            out[b * 42240 + (ocg * 16 + i) * 660 + yo * 30 + xx] = f2bf(acc[i]);
    }
}

// ---------------- fc1 as bf16 MFMA GEMM: C(128,256) = A(128,42240) @ W(256,42240)^T
// grid (66 k-chunks, 4 n-tiles), 4 waves/block; each wave: 128x16 strip, 8 acc frags.
// W converted fp32->bf16 (truncation) on the fly; partials to ws.
__global__ __launch_bounds__(256) void k_fc1_mfma(const unsigned short* __restrict__ A,
                                                  const float* __restrict__ W,
                                                  float* __restrict__ part) {
    int kc = blockIdx.x;  // 0..65, 640 K each
    int nb = blockIdx.y;  // 0..3, 64 N each
    int wave = threadIdx.x >> 6, lane = threadIdx.x & 63;
    int m16 = lane & 15, quad = lane >> 4;
    int n = nb * 64 + wave * 16 + m16;
    const float* wrow = W + (size_t)n * 42240;
    const unsigned short* abase = A + (size_t)m16 * 42240;
    f32x4 acc[8] = {};
    int k0 = kc * 640 + quad * 8;
    for (int ks = 0; ks < 20; ++ks) {
        int k = k0 + ks * 32;
        const uint32_t* wp = (const uint32_t*)(wrow + k);
        uint32_t u0 = wp[0], u1 = wp[1], u2 = wp[2], u3 = wp[3];
        uint32_t u4 = wp[4], u5 = wp[5], u6 = wp[6], u7 = wp[7];
        union { uint32_t u[4]; bf16x8 v; } bf;
        bf.u[0] = (u0 >> 16) | (u1 & 0xffff0000u);
        bf.u[1] = (u2 >> 16) | (u3 & 0xffff0000u);
        bf.u[2] = (u4 >> 16) | (u5 & 0xffff0000u);
        bf.u[3] = (u6 >> 16) | (u7 & 0xffff0000u);
#pragma unroll
        for (int tm = 0; tm < 8; ++tm) {
            bf16x8 af = *(const bf16x8*)(abase + (size_t)tm * 16 * 42240 + k);
            acc[tm] = __builtin_amdgcn_mfma_f32_16x16x32_bf16(af, bf.v, acc[tm], 0, 0, 0);
        }
    }
    float* pb = part + ((size_t)kc * 128) * 256 + n;
#pragma unroll
    for (int tm = 0; tm < 8; ++tm) {
        int row = tm * 16 + quad * 4;
#pragma unroll
        for (int r = 0; r < 4; ++r) pb[(size_t)(row + r) * 256] = acc[tm][r];
    }
}

__global__ __launch_bounds__(256) void k_fc1c(const float* __restrict__ part,
                                              const float* __restrict__ bias,
                                              float* __restrict__ o) {
    int b = blockIdx.x, n = threadIdx.x;
    float s = bias[n];
    for (int kc = 0; kc < 66; ++kc) s += part[((size_t)kc * 128 + b) * 256 + n];
    o[b * 256 + n] = fmaxf(s, 0.f);
}

// ---------------- fc2 + lowd1 + lowd2 fused -> cnn_out2 (h0/c0 source)
__global__ __launch_bounds__(128) void k_head(const float* __restrict__ f1o,
                                              const float* __restrict__ w2, const float* __restrict__ b2,
                                              const float* __restrict__ lw1, const float* __restrict__ lb1,
                                              const float* __restrict__ lw2, const float* __restrict__ lb2,
                                              float* __restrict__ cnn2) {
    int b = blockIdx.x, n = threadIdx.x;
    __shared__ float xa[256];
    __shared__ float xb[128];
    __shared__ float xc[128];
    xa[n] = f1o[b * 256 + n];
    xa[n + 128] = f1o[b * 256 + 128 + n];
    __syncthreads();
    float acc = b2[n];
    for (int k = 0; k < 256; ++k) acc = fmaf(xa[k], w2[n * 256 + k], acc);
    xb[n] = acc;  // cnn_out1, no relu
    __syncthreads();
    acc = lb1[n];
    for (int k = 0; k < 128; ++k) acc = fmaf(xb[k], lw1[n * 128 + k], acc);
    xc[n] = fmaxf(acc, 0.f);
    __syncthreads();
    acc = lb2[n];
    for (int k = 0; k < 128; ++k) acc = fmaf(xc[k], lw2[n * 128 + k], acc);
    cnn2[b * 128 + n] = acc;  // [:,:64]=c0, [:,64:]=h0
}

// ---------------- action MLP: (128,8,2) -> (128,8,16)
__global__ __launch_bounds__(256) void k_act(const float* __restrict__ ain,
                                             const float* __restrict__ w1, const float* __restrict__ b1,
                                             const float* __restrict__ w2, const float* __restrict__ b2,
                                             float* __restrict__ abuf) {
    int idx = blockIdx.x * 256 + threadIdx.x;  // b*8+t, 0..1023
    float x0 = ain[idx * 2], x1 = ain[idx * 2 + 1];
    float h1[16];
#pragma unroll
    for (int i = 0; i < 16; ++i)
        h1[i] = fmaxf(fmaf(x0, w1[i * 2], fmaf(x1, w1[i * 2 + 1], b1[i])), 0.f);
#pragma unroll
    for (int i = 0; i < 16; ++i) {
        float a = b2[i];
#pragma unroll
        for (int j = 0; j < 16; ++j) a = fmaf(h1[j], w2[i * 16 + j], a);
        abuf[idx * 16 + i] = a;
    }
}

// ---------------- LSTM: 8 layers x 8 steps, one sample per block, gate = thread,
// weights in VGPRs, x/h broadcast via v_readlane (avoids LDS-broadcast pipe bound)
__global__ __launch_bounds__(256) void k_lstm(const float* __restrict__ abuf,
                                              const float* __restrict__ cnn2,
                                              const float* __restrict__ Wih0,
                                              const float* __restrict__ Wih,
                                              const float* __restrict__ Whh,
                                              const float* __restrict__ bih,
                                              const float* __restrict__ bhh,
                                              float* __restrict__ lout) {
    int b = blockIdx.x, tid = threadIdx.x, lane = tid & 63;
    __shared__ float xs[8][64];
    __shared__ float gbuf[256];
    for (int i = tid; i < 512; i += 256) {
        int t = i >> 6, k = i & 63;
        xs[t][k] = (k < 16) ? abuf[(b * 8 + t) * 16 + k] : 0.f;
    }
    __syncthreads();
    for (int l = 0; l < 8; ++l) {
        float wih[64], whh[64];
        if (l == 0) {
#pragma unroll
            for (int k = 0; k < 64; ++k) wih[k] = (k < 16) ? Wih0[tid * 16 + k] : 0.f;
        } else {
#pragma unroll
            for (int k = 0; k < 64; ++k) wih[k] = Wih[((l - 1) * 256 + tid) * 64 + k];
        }
#pragma unroll
        for (int k = 0; k < 64; ++k) whh[k] = Whh[(l * 256 + tid) * 64 + k];
        float biasv = bih[l * 256 + tid] + bhh[l * 256 + tid];
        // h0/c0 broadcast to every layer
        float v_h = cnn2[b * 128 + 64 + lane];
        float v_c = cnn2[b * 128 + lane];
        for (int t = 0; t < 8; ++t) {
            float v_x = xs[t][lane];
            float a0 = biasv, a1 = 0.f, a2 = 0.f, a3 = 0.f;
#pragma unroll
            for (int k = 0; k < 64; k += 4) {
                a0 = fmaf(wih[k], bcastf(v_x, k), a0);
                a1 = fmaf(wih[k + 1], bcastf(v_x, k + 1), a1);
                a2 = fmaf(wih[k + 2], bcastf(v_x, k + 2), a2);
                a3 = fmaf(wih[k + 3], bcastf(v_x, k + 3), a3);
            }
#pragma unroll
            for (int k = 0; k < 64; k += 4) {
                a0 = fmaf(whh[k], bcastf(v_h, k), a0);
                a1 = fmaf(whh[k + 1], bcastf(v_h, k + 1), a1);
                a2 = fmaf(whh[k + 2], bcastf(v_h, k + 2), a2);
                a3 = fmaf(whh[k + 3], bcastf(v_h, k + 3), a3);
            }
            gbuf[tid] = (a0 + a1) + (a2 + a3);
            __syncthreads();
            // every wave redundantly updates its own h/c copy (lane = state index)
            float gi = gbuf[lane], gf = gbuf[64 + lane], gg = gbuf[128 + lane], go = gbuf[192 + lane];
            float cn = sigm(gf) * v_c + sigm(gi) * tanh_(gg);
            float hn = sigm(go) * tanh_(cn);
            v_c = cn;
            v_h = hn;
            if (tid < 64) xs[t][tid] = hn;  // becomes next layer's input
            __syncthreads();
        }
    }
    for (int i = tid; i < 512; i += 256) {
        int t = i >> 6, k = i & 63;
        lout[(b * 8 + t) * 64 + k] = xs[t][k];
    }
}

// ---------------- out MLP + rotation -> d_out (128,8,4)
__global__ __launch_bounds__(256) void k_out(const float* __restrict__ lout,
                                             const float* __restrict__ w1, const float* __restrict__ b1,
                                             const float* __restrict__ w2, const float* __restrict__ b2,
                                             const float* __restrict__ gt, float* __restrict__ out) {
    int idx = blockIdx.x * 256 + threadIdx.x;  // b*8+t
    int b = idx >> 3;
    float x[64];
#pragma unroll
    for (int j = 0; j < 64; ++j) x[j] = lout[idx * 64 + j];
    float h[32];
#pragma unroll 8
    for (int i = 0; i < 32; ++i) {
        float a = b1[i];
#pragma unroll
        for (int j = 0; j < 64; ++j) a = fmaf(x[j], w1[i * 64 + j], a);
        h[i] = fmaxf(a, 0.f);
    }
    float mo[4];
#pragma unroll
    for (int i = 0; i < 4; ++i) {
        float a = b2[i];
#pragma unroll
        for (int j = 0; j < 32; ++j) a = fmaf(h[j], w2[i * 32 + j], a);
        mo[i] = a;
    }
    float yaw = gt[b * 48 + 5];
    float cy = cosf(yaw), sy = sinf(yaw);
    out[idx * 4 + 0] = fmaf(mo[0], cy, fmaf(mo[1], sy, gt[b * 48 + 1]));
    out[idx * 4 + 1] = fmaf(mo[0], -sy, fmaf(mo[1], cy, gt[b * 48 + 2]));
    out[idx * 4 + 2] = mo[2] + gt[b * 48 + 3];
    out[idx * 4 + 3] = mo[3];
}

extern "C" void kernel_launch(void* const* d_in, const int* in_sizes, int n_in,
                              void* d_out, int out_size, void* d_ws, size_t ws_size,
                              hipStream_t stream) {
    const float* img = (const float*)d_in[0];
    const float* ain = (const float*)d_in[1];
    const float* gt = (const float*)d_in[2];
    const float* c1w = (const float*)d_in[3];
    const float* c1b = (const float*)d_in[4];
    const float* c2w = (const float*)d_in[5];
    const float* c2b = (const float*)d_in[6];
    const float* c3w = (const float*)d_in[7];
    const float* c3b = (const float*)d_in[8];
    const float* f1w = (const float*)d_in[9];
    const float* f1b = (const float*)d_in[10];
    const float* f2w = (const float*)d_in[11];
    const float* f2b = (const float*)d_in[12];
    const float* l1w = (const float*)d_in[13];
    const float* l1b = (const float*)d_in[14];
    const float* l2w = (const float*)d_in[15];
    const float* l2b = (const float*)d_in[16];
    const float* a1w = (const float*)d_in[17];
    const float* a1b = (const float*)d_in[18];
    const float* a2w = (const float*)d_in[19];
    const float* a2b = (const float*)d_in[20];
    const float* wih0 = (const float*)d_in[21];
    const float* wih = (const float*)d_in[22];
    const float* whh = (const float*)d_in[23];
    const float* bihp = (const float*)d_in[24];
    const float* bhhp = (const float*)d_in[25];
    const float* o1w = (const float*)d_in[26];
    const float* o1b = (const float*)d_in[27];
    const float* o2w = (const float*)d_in[28];
    const float* o2b = (const float*)d_in[29];
    float* out = (float*)d_out;

    char* ws = (char*)d_ws;
    unsigned short* c1o = (unsigned short*)(ws);                 // 48,513,024 bf16 = 97,026,048 B
    unsigned short* c2o = (unsigned short*)(ws + 97026048);      // 23,363,584 bf16 = 46,727,168 B
    unsigned short* c3o = (unsigned short*)(ws + 143753216);     // 5,406,720 bf16 = 10,813,440 B
    float* f1p = (float*)(ws + 154566656);                       // 66*128*256 f32 = 8,650,752 B
    float* f1o = (float*)(ws + 163217408);                       // 128*256 f32
    float* cnn2 = (float*)(ws + 163348480);                      // 128*128
    float* abuf = (float*)(ws + 163414016);                      // 128*8*16
    float* lo = (float*)(ws + 163479552);                        // 128*8*64

    k_conv1<<<dim3(94, 128), 128, 0, stream>>>(img, c1w, c1b, c1o);
    k_conv2<<<dim3(46, 128), 256, 0, stream>>>(c1o, c2w, c2b, c2o);
    k_conv3<<<dim3(11, 128), 256, 0, stream>>>(c2o, c3w, c3b, c3o);
    k_fc1_mfma<<<dim3(66, 4), 256, 0, stream>>>(c3o, f1w, f1p);
    k_fc1c<<<128, 256, 0, stream>>>(f1p, f1b, f1o);
    k_head<<<128, 128, 0, stream>>>(f1o, f2w, f2b, l1w, l1b, l2w, l2b, cnn2);
    k_act<<<4, 256, 0, stream>>>(ain, a1w, a1b, a2w, a2b, abuf);
    k_lstm<<<128, 256, 0, stream>>>(abuf, cnn2, wih0, wih, whh, bihp, bhhp, lo);
    k_out<<<4, 256, 0, stream>>>(lo, o1w, o1b, o2w, o2b, gt, out);
}

// Round 3
// 640.668 us; speedup vs baseline: 2.8268x; 1.6712x over previous
//
#include <hip/hip_runtime.h>
#include <cstdint>

#define DEV __device__ __forceinline__

typedef __attribute__((ext_vector_type(8))) short bf16x8;
typedef __attribute__((ext_vector_type(4))) float f32x4;

DEV unsigned short f2bf(float f) {
    unsigned u = __float_as_uint(f);
    unsigned r = u + 0x7fffu + ((u >> 16) & 1u);
    return (unsigned short)(r >> 16);
}
DEV float bcastf(float v, int k) {
    return __uint_as_float(__builtin_amdgcn_readlane((int)__float_as_uint(v), k));
}
DEV float sigm(float x) { return 1.f / (1.f + __expf(-x)); }
DEV float tanh_(float x) {
    x = fminf(fmaxf(x, -15.f), 15.f);
    float e = __expf(2.f * x);
    return (e - 1.f) / (e + 1.f);
}

// ---------------- weight prep: transpose conv weights to k-chunk order, bf16
// w1t[oc][k], k=(r*5+kx)*3+c, K=75 padded to 96 (pad=0)
// w2t[oc][k], k=(r*3+kx)*32+c, K=288
// w3t[oc][k], k=(r*3+kx)*64+c, K=576
__global__ __launch_bounds__(256) void k_wprep(const float* __restrict__ w1,
                                               const float* __restrict__ w2,
                                               const float* __restrict__ w3,
                                               unsigned short* __restrict__ w1t,
                                               unsigned short* __restrict__ w2t,
                                               unsigned short* __restrict__ w3t) {
    int i = blockIdx.x * 256 + threadIdx.x;
    if (i < 32 * 96) {
        int oc = i / 96, k = i - oc * 96;
        int pos = k / 3, c = k - pos * 3;
        w1t[i] = (k < 75) ? f2bf(w1[oc * 75 + c * 25 + pos]) : (unsigned short)0;
    } else if (i < 32 * 96 + 64 * 288) {
        int j = i - 32 * 96;
        int oc = j / 288, k = j - oc * 288;
        int pos = k >> 5, c = k & 31;
        w2t[j] = f2bf(w2[oc * 288 + c * 9 + pos]);
    } else if (i < 32 * 96 + 64 * 288 + 64 * 576) {
        int j = i - 32 * 96 - 64 * 288;
        int oc = j / 576, k = j - oc * 576;
        int pos = k >> 6, c = k & 63;
        w3t[j] = f2bf(w3[oc * 576 + c * 9 + pos]);
    }
}

// ---------------- conv1 MFMA: (128,3,192,256) -> (128,32,94,126), 5x5 s2, ReLU, bf16 out
// block = (y, b); M=32 oc (2 mt), N=126 px (8 nt), K=96 (3 chunks)
__global__ __launch_bounds__(256) void k_conv1m(const float* __restrict__ img,
                                                const unsigned short* __restrict__ w1t,
                                                const float* __restrict__ bias,
                                                unsigned short* __restrict__ out) {
    int y = blockIdx.x, b = blockIdx.y;
    int tid = threadIdx.x;
    __shared__ __align__(16) unsigned short bfrag[3 * 8 * 64 * 8];  // 24576 B
    uint32_t* bz = (uint32_t*)bfrag;
    for (int u = tid; u < 6144; u += 256) bz[u] = 0;
    __syncthreads();
    for (int u = tid; u < 3840; u += 256) {
        int pair = u >> 8, p = u & 255;
        int c = pair / 5, r = pair - c * 5;
        float fv = img[((size_t)(b * 3 + c) * 192 + 2 * y + r) * 256 + p];
        unsigned short e = f2bf(fv);
        int pr5 = r * 5;
        if ((p & 1) == 0) {
            int h = p >> 1;
#pragma unroll
            for (int kk = 0; kk < 3; ++kk) {
                int x = h - kk;
                if (x >= 0 && x < 126) {
                    int k = (pr5 + kk * 2) * 3 + c;
                    bfrag[((k >> 5) * 8 + (x >> 4)) * 512 + ((k & 31) >> 3) * 128 + (x & 15) * 8 + (k & 7)] = e;
                }
            }
        } else {
            int h = (p - 1) >> 1;
#pragma unroll
            for (int kk = 0; kk < 2; ++kk) {
                int x = h - kk;
                if (x >= 0 && x < 126) {
                    int k = (pr5 + kk * 2 + 1) * 3 + c;
                    bfrag[((k >> 5) * 8 + (x >> 4)) * 512 + ((k & 31) >> 3) * 128 + (x & 15) * 8 + (k & 7)] = e;
                }
            }
        }
    }
    __syncthreads();
    int wave = tid >> 6, lane = tid & 63;
    int quad = lane >> 4, nl = lane & 15;
    int mt = wave & 1, ng = wave >> 1;
    float4 bv = *(const float4*)(bias + mt * 16 + quad * 4);
    f32x4 acc[4];
#pragma unroll
    for (int q = 0; q < 4; ++q) { acc[q][0] = bv.x; acc[q][1] = bv.y; acc[q][2] = bv.z; acc[q][3] = bv.w; }
    const unsigned short* wbase = w1t + (mt * 16 + nl) * 96 + quad * 8;
#pragma unroll
    for (int ks = 0; ks < 3; ++ks) {
        bf16x8 af = *(const bf16x8*)(wbase + ks * 32);
#pragma unroll
        for (int q = 0; q < 4; ++q) {
            bf16x8 bfv = *(const bf16x8*)(&bfrag[(ks * 8 + ng * 4 + q) * 512 + lane * 8]);
            acc[q] = __builtin_amdgcn_mfma_f32_16x16x32_bf16(af, bfv, acc[q], 0, 0, 0);
        }
    }
    int oc_o = mt * 16 + quad * 4;
#pragma unroll
    for (int q = 0; q < 4; ++q) {
        int x = (ng * 4 + q) * 16 + nl;
        if (x < 126) {
#pragma unroll
            for (int r2 = 0; r2 < 4; ++r2)
                out[((size_t)(b * 32 + oc_o + r2) * 94 + y) * 126 + x] = f2bf(fmaxf(acc[q][r2], 0.f));
        }
    }
}

// ---------------- conv2 MFMA: (128,32,94,126) -> (128,64,46,62), 3x3 s2, ReLU, bf16 in/out
// block = (y, b); M=64 oc (4 mt=waves), N=62 px (4 nt), K=288 (9 chunks)
__global__ __launch_bounds__(256) void k_conv2m(const unsigned short* __restrict__ in,
                                                const unsigned short* __restrict__ w2t,
                                                const float* __restrict__ bias,
                                                unsigned short* __restrict__ out) {
    int y = blockIdx.x, b = blockIdx.y;
    int tid = threadIdx.x;
    __shared__ __align__(16) unsigned short bfrag[9 * 4 * 64 * 8];  // 36864 B
    const uint32_t* inp = (const uint32_t*)in;
    for (int u = tid; u < 6048; u += 256) {
        int pair = u / 63, p = u - pair * 63;
        int c = pair / 3, r = pair - c * 3;
        uint32_t v = inp[((size_t)(b * 32 + c) * 94 + 2 * y + r) * 63 + p];
        unsigned short e0 = (unsigned short)(v & 0xffffu);
        unsigned short e1 = (unsigned short)(v >> 16);
        int quad128 = ((c >> 3) & 3) * 128, j = c & 7;
        int br = r * 3;
        if (p < 62) {
            bfrag[(br * 4 + (p >> 4)) * 512 + quad128 + (p & 15) * 8 + j] = e0;
            bfrag[((br + 1) * 4 + (p >> 4)) * 512 + quad128 + (p & 15) * 8 + j] = e1;
        }
        if (p >= 1) {
            int x = p - 1;
            bfrag[((br + 2) * 4 + (x >> 4)) * 512 + quad128 + (x & 15) * 8 + j] = e0;
        }
    }
    __syncthreads();
    int wave = tid >> 6, lane = tid & 63;
    int quad = lane >> 4, nl = lane & 15;
    float4 bv = *(const float4*)(bias + wave * 16 + quad * 4);
    f32x4 acc[4];
#pragma unroll
    for (int q = 0; q < 4; ++q) { acc[q][0] = bv.x; acc[q][1] = bv.y; acc[q][2] = bv.z; acc[q][3] = bv.w; }
    const unsigned short* wbase = w2t + (wave * 16 + nl) * 288 + quad * 8;
    for (int ks = 0; ks < 9; ++ks) {
        bf16x8 af = *(const bf16x8*)(wbase + ks * 32);
#pragma unroll
        for (int nt = 0; nt < 4; ++nt) {
            bf16x8 bfv = *(const bf16x8*)(&bfrag[(ks * 4 + nt) * 512 + lane * 8]);
            acc[nt] = __builtin_amdgcn_mfma_f32_16x16x32_bf16(af, bfv, acc[nt], 0, 0, 0);
        }
    }
    int oc_o = wave * 16 + quad * 4;
#pragma unroll
    for (int nt = 0; nt < 4; ++nt) {
        int x = nt * 16 + nl;
        if (x < 62) {
#pragma unroll
            for (int r2 = 0; r2 < 4; ++r2)
                out[((size_t)(b * 64 + oc_o + r2) * 46 + y) * 62 + x] = f2bf(fmaxf(acc[nt][r2], 0.f));
        }
    }
}

// ---------------- conv3 MFMA: (128,64,46,62) -> (128,64,22,30), 3x3 s2, no relu,
// bf16 out in flatten (C,H,W) layout. block = (y, b); M=64 oc, N=30 px (2 nt), K=576 (18 chunks)
__global__ __launch_bounds__(256) void k_conv3m(const unsigned short* __restrict__ in,
                                                const unsigned short* __restrict__ w3t,
                                                const float* __restrict__ bias,
                                                unsigned short* __restrict__ out) {
    int y = blockIdx.x, b = blockIdx.y;
    int tid = threadIdx.x;
    __shared__ __align__(16) unsigned short bfrag[18 * 2 * 64 * 8];  // 36864 B
    const uint32_t* inp = (const uint32_t*)in;
    for (int u = tid; u < 5952; u += 256) {
        int pair = u / 31, p = u - pair * 31;
        int c = pair / 3, r = pair - c * 3;
        uint32_t v = inp[((size_t)(b * 64 + c) * 46 + 2 * y + r) * 31 + p];
        unsigned short e0 = (unsigned short)(v & 0xffffu);
        unsigned short e1 = (unsigned short)(v >> 16);
        int quad128 = ((c & 31) >> 3) * 128, j = c & 7;
        int ch = c >> 5;
        int br = r * 3;
        if (p < 30) {
            bfrag[((br * 2 + ch) * 2 + (p >> 4)) * 512 + quad128 + (p & 15) * 8 + j] = e0;
            bfrag[(((br + 1) * 2 + ch) * 2 + (p >> 4)) * 512 + quad128 + (p & 15) * 8 + j] = e1;
        }
        if (p >= 1) {
            int x = p - 1;
            bfrag[(((br + 2) * 2 + ch) * 2 + (x >> 4)) * 512 + quad128 + (x & 15) * 8 + j] = e0;
        }
    }
    __syncthreads();
    int wave = tid >> 6, lane = tid & 63;
    int quad = lane >> 4, nl = lane & 15;
    float4 bv = *(const float4*)(bias + wave * 16 + quad * 4);
    f32x4 acc[2];
#pragma unroll
    for (int q = 0; q < 2; ++q) { acc[q][0] = bv.x; acc[q][1] = bv.y; acc[q][2] = bv.z; acc[q][3] = bv.w; }
    const unsigned short* wbase = w3t + (wave * 16 + nl) * 576 + quad * 8;
    for (int ks = 0; ks < 18; ++ks) {
        bf16x8 af = *(const bf16x8*)(wbase + ks * 32);
#pragma unroll
        for (int nt = 0; nt < 2; ++nt) {
            bf16x8 bfv = *(const bf16x8*)(&bfrag[(ks * 2 + nt) * 512 + lane * 8]);
            acc[nt] = __builtin_amdgcn_mfma_f32_16x16x32_bf16(af, bfv, acc[nt], 0, 0, 0);
        }
    }
    int oc_o = wave * 16 + quad * 4;
#pragma unroll
    for (int nt = 0; nt < 2; ++nt) {
        int x = nt * 16 + nl;
        if (x < 30) {
#pragma unroll
            for (int r2 = 0; r2 < 4; ++r2)
                out[(size_t)b * 42240 + (oc_o + r2) * 660 + y * 30 + x] = f2bf(acc[nt][r2]);
        }
    }
}

// ---------------- fc1 as bf16 MFMA GEMM: C(128,256) = A(128,42240) @ W(256,42240)^T
__global__ __launch_bounds__(256) void k_fc1_mfma(const unsigned short* __restrict__ A,
                                                  const float* __restrict__ W,
                                                  float* __restrict__ part) {
    int kc = blockIdx.x;  // 0..65, 640 K each
    int nb = blockIdx.y;  // 0..3, 64 N each
    int wave = threadIdx.x >> 6, lane = threadIdx.x & 63;
    int m16 = lane & 15, quad = lane >> 4;
    int n = nb * 64 + wave * 16 + m16;
    const float* wrow = W + (size_t)n * 42240;
    const unsigned short* abase = A + (size_t)m16 * 42240;
    f32x4 acc[8] = {};
    int k0 = kc * 640 + quad * 8;
    for (int ks = 0; ks < 20; ++ks) {
        int k = k0 + ks * 32;
        const uint32_t* wp = (const uint32_t*)(wrow + k);
        uint32_t u0 = wp[0], u1 = wp[1], u2 = wp[2], u3 = wp[3];
        uint32_t u4 = wp[4], u5 = wp[5], u6 = wp[6], u7 = wp[7];
        union { uint32_t u[4]; bf16x8 v; } bf;
        bf.u[0] = (u0 >> 16) | (u1 & 0xffff0000u);
        bf.u[1] = (u2 >> 16) | (u3 & 0xffff0000u);
        bf.u[2] = (u4 >> 16) | (u5 & 0xffff0000u);
        bf.u[3] = (u6 >> 16) | (u7 & 0xffff0000u);
#pragma unroll
        for (int tm = 0; tm < 8; ++tm) {
            bf16x8 af = *(const bf16x8*)(abase + (size_t)tm * 16 * 42240 + k);
            acc[tm] = __builtin_amdgcn_mfma_f32_16x16x32_bf16(af, bf.v, acc[tm], 0, 0, 0);
        }
    }
    float* pb = part + ((size_t)kc * 128) * 256 + n;
#pragma unroll
    for (int tm = 0; tm < 8; ++tm) {
        int row = tm * 16 + quad * 4;
#pragma unroll
        for (int r = 0; r < 4; ++r) pb[(size_t)(row + r) * 256] = acc[tm][r];
    }
}

__global__ __launch_bounds__(256) void k_fc1c(const float* __restrict__ part,
                                              const float* __restrict__ bias,
                                              float* __restrict__ o) {
    int b = blockIdx.x, n = threadIdx.x;
    float s = bias[n];
    for (int kc = 0; kc < 66; ++kc) s += part[((size_t)kc * 128 + b) * 256 + n];
    o[b * 256 + n] = fmaxf(s, 0.f);
}

// ---------------- fc2 + lowd1 + lowd2 fused -> cnn_out2 (h0/c0 source)
__global__ __launch_bounds__(128) void k_head(const float* __restrict__ f1o,
                                              const float* __restrict__ w2, const float* __restrict__ b2,
                                              const float* __restrict__ lw1, const float* __restrict__ lb1,
                                              const float* __restrict__ lw2, const float* __restrict__ lb2,
                                              float* __restrict__ cnn2) {
    int b = blockIdx.x, n = threadIdx.x;
    __shared__ float xa[256];
    __shared__ float xb[128];
    __shared__ float xc[128];
    xa[n] = f1o[b * 256 + n];
    xa[n + 128] = f1o[b * 256 + 128 + n];
    __syncthreads();
    float acc = b2[n];
    for (int k = 0; k < 256; ++k) acc = fmaf(xa[k], w2[n * 256 + k], acc);
    xb[n] = acc;  // cnn_out1, no relu
    __syncthreads();
    acc = lb1[n];
    for (int k = 0; k < 128; ++k) acc = fmaf(xb[k], lw1[n * 128 + k], acc);
    xc[n] = fmaxf(acc, 0.f);
    __syncthreads();
    acc = lb2[n];
    for (int k = 0; k < 128; ++k) acc = fmaf(xc[k], lw2[n * 128 + k], acc);
    cnn2[b * 128 + n] = acc;  // [:,:64]=c0, [:,64:]=h0
}

// ---------------- action MLP: (128,8,2) -> (128,8,16)
__global__ __launch_bounds__(256) void k_act(const float* __restrict__ ain,
                                             const float* __restrict__ w1, const float* __restrict__ b1,
                                             const float* __restrict__ w2, const float* __restrict__ b2,
                                             float* __restrict__ abuf) {
    int idx = blockIdx.x * 256 + threadIdx.x;
    float x0 = ain[idx * 2], x1 = ain[idx * 2 + 1];
    float h1[16];
#pragma unroll
    for (int i = 0; i < 16; ++i)
        h1[i] = fmaxf(fmaf(x0, w1[i * 2], fmaf(x1, w1[i * 2 + 1], b1[i])), 0.f);
#pragma unroll
    for (int i = 0; i < 16; ++i) {
        float a = b2[i];
#pragma unroll
        for (int j = 0; j < 16; ++j) a = fmaf(h1[j], w2[i * 16 + j], a);
        abuf[idx * 16 + i] = a;
    }
}

// ---------------- LSTM: 8 layers x 8 steps, one sample per block
__global__ __launch_bounds__(256) void k_lstm(const float* __restrict__ abuf,
                                              const float* __restrict__ cnn2,
                                              const float* __restrict__ Wih0,
                                              const float* __restrict__ Wih,
                                              const float* __restrict__ Whh,
                                              const float* __restrict__ bih,
                                              const float* __restrict__ bhh,
                                              float* __restrict__ lout) {
    int b = blockIdx.x, tid = threadIdx.x, lane = tid & 63;
    __shared__ float xs[8][64];
    __shared__ float gbuf[256];
    for (int i = tid; i < 512; i += 256) {
        int t = i >> 6, k = i & 63;
        xs[t][k] = (k < 16) ? abuf[(b * 8 + t) * 16 + k] : 0.f;
    }
    __syncthreads();
    for (int l = 0; l < 8; ++l) {
        float wih[64], whh[64];
        if (l == 0) {
#pragma unroll
            for (int k = 0; k < 64; ++k) wih[k] = (k < 16) ? Wih0[tid * 16 + k] : 0.f;
        } else {
#pragma unroll
            for (int k = 0; k < 64; ++k) wih[k] = Wih[((l - 1) * 256 + tid) * 64 + k];
        }
#pragma unroll
        for (int k = 0; k < 64; ++k) whh[k] = Whh[(l * 256 + tid) * 64 + k];
        float biasv = bih[l * 256 + tid] + bhh[l * 256 + tid];
        float v_h = cnn2[b * 128 + 64 + lane];
        float v_c = cnn2[b * 128 + lane];
        for (int t = 0; t < 8; ++t) {
            float v_x = xs[t][lane];
            float a0 = biasv, a1 = 0.f, a2 = 0.f, a3 = 0.f;
#pragma unroll
            for (int k = 0; k < 64; k += 4) {
                a0 = fmaf(wih[k], bcastf(v_x, k), a0);
                a1 = fmaf(wih[k + 1], bcastf(v_x, k + 1), a1);
                a2 = fmaf(wih[k + 2], bcastf(v_x, k + 2), a2);
                a3 = fmaf(wih[k + 3], bcastf(v_x, k + 3), a3);
            }
#pragma unroll
            for (int k = 0; k < 64; k += 4) {
                a0 = fmaf(whh[k], bcastf(v_h, k), a0);
                a1 = fmaf(whh[k + 1], bcastf(v_h, k + 1), a1);
                a2 = fmaf(whh[k + 2], bcastf(v_h, k + 2), a2);
                a3 = fmaf(whh[k + 3], bcastf(v_h, k + 3), a3);
            }
            gbuf[tid] = (a0 + a1) + (a2 + a3);
            __syncthreads();
            float gi = gbuf[lane], gf = gbuf[64 + lane], gg = gbuf[128 + lane], go = gbuf[192 + lane];
            float cn = sigm(gf) * v_c + sigm(gi) * tanh_(gg);
            float hn = sigm(go) * tanh_(cn);
            v_c = cn;
            v_h = hn;
            if (tid < 64) xs[t][tid] = hn;
            __syncthreads();
        }
    }
    for (int i = tid; i < 512; i += 256) {
        int t = i >> 6, k = i & 63;
        lout[(b * 8 + t) * 64 + k] = xs[t][k];
    }
}

// ---------------- out MLP + rotation -> d_out (128,8,4)
__global__ __launch_bounds__(256) void k_out(const float* __restrict__ lout,
                                             const float* __restrict__ w1, const float* __restrict__ b1,
                                             const float* __restrict__ w2, const float* __restrict__ b2,
                                             const float* __restrict__ gt, float* __restrict__ out) {
    int idx = blockIdx.x * 256 + threadIdx.x;
    int b = idx >> 3;
    float x[64];
#pragma unroll
    for (int j = 0; j < 64; ++j) x[j] = lout[idx * 64 + j];
    float h[32];
#pragma unroll 8
    for (int i = 0; i < 32; ++i) {
        float a = b1[i];
#pragma unroll
        for (int j = 0; j < 64; ++j) a = fmaf(x[j], w1[i * 64 + j], a);
        h[i] = fmaxf(a, 0.f);
    }
    float mo[4];
#pragma unroll
    for (int i = 0; i < 4; ++i) {
        float a = b2[i];
#pragma unroll
        for (int j = 0; j < 32; ++j) a = fmaf(h[j], w2[i * 32 + j], a);
        mo[i] = a;
    }
    float yaw = gt[b * 48 + 5];
    float cy = cosf(yaw), sy = sinf(yaw);
    out[idx * 4 + 0] = fmaf(mo[0], cy, fmaf(mo[1], sy, gt[b * 48 + 1]));
    out[idx * 4 + 1] = fmaf(mo[0], -sy, fmaf(mo[1], cy, gt[b * 48 + 2]));
    out[idx * 4 + 2] = mo[2] + gt[b * 48 + 3];
    out[idx * 4 + 3] = mo[3];
}

extern "C" void kernel_launch(void* const* d_in, const int* in_sizes, int n_in,
                              void* d_out, int out_size, void* d_ws, size_t ws_size,
                              hipStream_t stream) {
    const float* img = (const float*)d_in[0];
    const float* ain = (const float*)d_in[1];
    const float* gt = (const float*)d_in[2];
    const float* c1w = (const float*)d_in[3];
    const float* c1b = (const float*)d_in[4];
    const float* c2w = (const float*)d_in[5];
    const float* c2b = (const float*)d_in[6];
    const float* c3w = (const float*)d_in[7];
    const float* c3b = (const float*)d_in[8];
    const float* f1w = (const float*)d_in[9];
    const float* f1b = (const float*)d_in[10];
    const float* f2w = (const float*)d_in[11];
    const float* f2b = (const float*)d_in[12];
    const float* l1w = (const float*)d_in[13];
    const float* l1b = (const float*)d_in[14];
    const float* l2w = (const float*)d_in[15];
    const float* l2b = (const float*)d_in[16];
    const float* a1w = (const float*)d_in[17];
    const float* a1b = (const float*)d_in[18];
    const float* a2w = (const float*)d_in[19];
    const float* a2b = (const float*)d_in[20];
    const float* wih0 = (const float*)d_in[21];
    const float* wih = (const float*)d_in[22];
    const float* whh = (const float*)d_in[23];
    const float* bihp = (const float*)d_in[24];
    const float* bhhp = (const float*)d_in[25];
    const float* o1w = (const float*)d_in[26];
    const float* o1b = (const float*)d_in[27];
    const float* o2w = (const float*)d_in[28];
    const float* o2b = (const float*)d_in[29];
    float* out = (float*)d_out;

    char* ws = (char*)d_ws;
    unsigned short* c1o = (unsigned short*)(ws);                 // 97,026,048 B
    unsigned short* c2o = (unsigned short*)(ws + 97026048);      // 46,727,168 B
    unsigned short* c3o = (unsigned short*)(ws + 143753216);     // 10,813,440 B
    float* f1p = (float*)(ws + 154566656);                       // 8,650,752 B
    float* f1o = (float*)(ws + 163217408);                       // 131,072 B
    float* cnn2 = (float*)(ws + 163348480);                      // 65,536 B
    float* abuf = (float*)(ws + 163414016);                      // 65,536 B
    float* lo = (float*)(ws + 163479552);                        // 262,144 B
    unsigned short* w1t = (unsigned short*)(ws + 163741696);     // 6,144 B
    unsigned short* w2t = (unsigned short*)(ws + 163747840);     // 36,864 B
    unsigned short* w3t = (unsigned short*)(ws + 163784704);     // 73,728 B

    k_wprep<<<228, 256, 0, stream>>>(c1w, c2w, c3w, w1t, w2t, w3t);
    k_conv1m<<<dim3(94, 128), 256, 0, stream>>>(img, w1t, c1b, c1o);
    k_conv2m<<<dim3(46, 128), 256, 0, stream>>>(c1o, w2t, c2b, c2o);
    k_conv3m<<<dim3(22, 128), 256, 0, stream>>>(c2o, w3t, c3b, c3o);
    k_fc1_mfma<<<dim3(66, 4), 256, 0, stream>>>(c3o, f1w, f1p);
    k_fc1c<<<128, 256, 0, stream>>>(f1p, f1b, f1o);
    k_head<<<128, 128, 0, stream>>>(f1o, f2w, f2b, l1w, l1b, l2w, l2b, cnn2);
    k_act<<<4, 256, 0, stream>>>(ain, a1w, a1b, a2w, a2b, abuf);
    k_lstm<<<128, 256, 0, stream>>>(abuf, cnn2, wih0, whh == nullptr ? nullptr : wih, whh, bihp, bhhp, lo);
    k_out<<<4, 256, 0, stream>>>(lo, o1w, o1b, o2w, o2b, gt, out);
}

// Round 4
// 541.687 us; speedup vs baseline: 3.3433x; 1.1827x over previous
//
#include <hip/hip_runtime.h>
#include <cstdint>

#define DEV __device__ __forceinline__

typedef __attribute__((ext_vector_type(8))) short bf16x8;
typedef __attribute__((ext_vector_type(4))) float f32x4;
typedef unsigned long long u64;

DEV unsigned short f2bf(float f) {
    unsigned u = __float_as_uint(f);
    unsigned r = u + 0x7fffu + ((u >> 16) & 1u);
    return (unsigned short)(r >> 16);
}
DEV float bcastf(float v, int k) {
    return __uint_as_float(__builtin_amdgcn_readlane((int)__float_as_uint(v), k));
}
DEV float sigm(float x) { return 1.f / (1.f + __expf(-x)); }
DEV float tanh_(float x) {
    x = fminf(fmaxf(x, -15.f), 15.f);
    float e = __expf(2.f * x);
    return (e - 1.f) / (e + 1.f);
}
DEV u64 pack4bf(float a, float b, float c, float d) {
    unsigned lo = (unsigned)f2bf(a) | ((unsigned)f2bf(b) << 16);
    unsigned hi = (unsigned)f2bf(c) | ((unsigned)f2bf(d) << 16);
    return (u64)lo | ((u64)hi << 32);
}

// ---------------- weight prep (bf16, K-chunk order)
// w1t[32][128]: k = tap*4 + c, tap=r*5+kx (<25), c<3 valid else 0
// w2t[64][288]: k = tap*32 + c, tap=r*3+kx
// w3t[64][576]: k = tap*64 + c
__global__ __launch_bounds__(256) void k_wprep(const float* __restrict__ w1,
                                               const float* __restrict__ w2,
                                               const float* __restrict__ w3,
                                               unsigned short* __restrict__ w1t,
                                               unsigned short* __restrict__ w2t,
                                               unsigned short* __restrict__ w3t) {
    int i = blockIdx.x * 256 + threadIdx.x;
    if (i < 32 * 128) {
        int oc = i >> 7, k = i & 127;
        int tap = k >> 2, c = k & 3;
        w1t[i] = (tap < 25 && c < 3) ? f2bf(w1[oc * 75 + c * 25 + tap]) : (unsigned short)0;
    } else if (i < 32 * 128 + 64 * 288) {
        int j = i - 32 * 128;
        int oc = j / 288, k = j - oc * 288;
        int pos = k >> 5, c = k & 31;
        w2t[j] = f2bf(w2[oc * 288 + c * 9 + pos]);
    } else if (i < 32 * 128 + 64 * 288 + 64 * 576) {
        int j = i - 32 * 128 - 64 * 288;
        int oc = j / 576, k = j - oc * 576;
        int pos = k >> 6, c = k & 63;
        w3t[j] = f2bf(w3[oc * 576 + c * 9 + pos]);
    }
}

// ---------------- conv1: NCHW fp32 img -> NHWC c1o[b][y][x][32] bf16. 5x5 s2 ReLU.
// M=32 oc (2 mt), N=126 px (8 nt), K=128 (4 chunks of 8 taps x 4ch)
__global__ __launch_bounds__(256) void k_conv1m(const float* __restrict__ img,
                                                const unsigned short* __restrict__ w1t,
                                                const float* __restrict__ bias,
                                                unsigned short* __restrict__ out) {
    int b = blockIdx.x, y = blockIdx.y;
    int tid = threadIdx.x;
    // 7 rows x 260 px x 4ch bf16: row stride 2080 B; rows 5,6 = zero pad taps
    __shared__ __align__(16) unsigned short lds[7 * 1040];
    char* lb = (char*)lds;
    uint32_t* z32 = (uint32_t*)(lb + 5 * 2080);
    for (int u = tid; u < 1040; u += 256) z32[u] = 0;
    const float* ibase = img + (size_t)b * 3 * 192 * 256 + (size_t)(2 * y) * 256;
    for (int u = tid; u < 1280; u += 256) {
        int r = u >> 8, p = u & 255;
        const float* ip = ibase + r * 256 + p;
        float f0 = ip[0], f1 = ip[192 * 256], f2 = ip[2 * 192 * 256];
        uint32_t lo = (uint32_t)f2bf(f0) | ((uint32_t)f2bf(f1) << 16);
        uint32_t hi = (uint32_t)f2bf(f2);
        *(u64*)(lb + r * 2080 + p * 8) = (u64)lo | ((u64)hi << 32);
    }
    __syncthreads();
    int wave = tid >> 6, lane = tid & 63;
    int quad = lane >> 4, nl = lane & 15;
    int mt = wave & 1, ntg = wave >> 1;  // 4 nt tiles each
    float4 bv = *(const float4*)(bias + mt * 16 + quad * 4);
    f32x4 acc[4];
#pragma unroll
    for (int q = 0; q < 4; ++q) { acc[q][0] = bv.x; acc[q][1] = bv.y; acc[q][2] = bv.z; acc[q][3] = bv.w; }
    const unsigned short* wbase = w1t + (mt * 16 + nl) * 128 + quad * 8;
#pragma unroll
    for (int ks = 0; ks < 4; ++ks) {
        bf16x8 af = *(const bf16x8*)(wbase + ks * 32);
        int t0 = ks * 8 + quad * 2;
        int r0 = t0 / 5, kx0 = t0 - r0 * 5;
        int t1 = t0 + 1;
        int r1 = t1 / 5, kx1 = t1 - r1 * 5;
        int ro0 = r0 * 2080 + kx0 * 8;
        int ro1 = r1 * 2080 + kx1 * 8;
#pragma unroll
        for (int q = 0; q < 4; ++q) {
            int x = (ntg * 4 + q) * 16 + nl;
            union { u64 d[2]; bf16x8 v; } bb;
            bb.d[0] = *(const u64*)(lb + ro0 + x * 16);
            bb.d[1] = *(const u64*)(lb + ro1 + x * 16);
            acc[q] = __builtin_amdgcn_mfma_f32_16x16x32_bf16(af, bb.v, acc[q], 0, 0, 0);
        }
    }
    int oc0 = mt * 16 + quad * 4;
#pragma unroll
    for (int q = 0; q < 4; ++q) {
        int x = (ntg * 4 + q) * 16 + nl;
        if (x < 126) {
            u64 pk = pack4bf(fmaxf(acc[q][0], 0.f), fmaxf(acc[q][1], 0.f),
                             fmaxf(acc[q][2], 0.f), fmaxf(acc[q][3], 0.f));
            *(u64*)(out + (((size_t)b * 94 + y) * 126 + x) * 32 + oc0) = pk;
        }
    }
}

// ---------------- conv2: NHWC in [128][94][126][32] -> NHWC out [128][46][62][64]. 3x3 s2 ReLU.
// M=64 (4 mt), N=62 (4 nt), K=288 (9 chunks = taps). Wave covers 2mt x 2nt.
__global__ __launch_bounds__(256) void k_conv2m(const unsigned short* __restrict__ in,
                                                const unsigned short* __restrict__ w2t,
                                                const float* __restrict__ bias,
                                                unsigned short* __restrict__ out) {
    int b = blockIdx.x, y = blockIdx.y;
    int tid = threadIdx.x;
    // 3 rows x 130 px, pixel stride 72 B (64 data + 8 pad) -> bank grp = 4x%32, 2-way free
    __shared__ __align__(16) unsigned short lds[3 * 130 * 36];
    char* lb = (char*)lds;
    const u64* in64 = (const u64*)in;
    size_t gbase = ((size_t)b * 94 + 2 * y) * 126 * 8;
    for (int u = tid; u < 3024; u += 256) {
        int r = u / 1008, rem = u - r * 1008;
        int p = rem >> 3, h = rem & 7;
        u64 v = in64[gbase + (size_t)r * 126 * 8 + p * 8 + h];
        *(u64*)(lb + r * 9360 + p * 72 + h * 8) = v;
    }
    __syncthreads();
    int wave = tid >> 6, lane = tid & 63;
    int quad = lane >> 4, nl = lane & 15;
    int mtg = wave & 1, ntg = wave >> 1;
    f32x4 acc[4];
#pragma unroll
    for (int mi = 0; mi < 2; ++mi) {
        float4 bv = *(const float4*)(bias + (mtg * 2 + mi) * 16 + quad * 4);
#pragma unroll
        for (int ni = 0; ni < 2; ++ni) {
            acc[mi * 2 + ni][0] = bv.x; acc[mi * 2 + ni][1] = bv.y;
            acc[mi * 2 + ni][2] = bv.z; acc[mi * 2 + ni][3] = bv.w;
        }
    }
#pragma unroll
    for (int ks = 0; ks < 9; ++ks) {
        const int r = ks / 3, kx = ks - r * 3;
        bf16x8 af0 = *(const bf16x8*)(w2t + ((mtg * 2 + 0) * 16 + nl) * 288 + ks * 32 + quad * 8);
        bf16x8 af1 = *(const bf16x8*)(w2t + ((mtg * 2 + 1) * 16 + nl) * 288 + ks * 32 + quad * 8);
        int ro = r * 9360 + 72 * kx + quad * 16;
#pragma unroll
        for (int ni = 0; ni < 2; ++ni) {
            int x = (ntg * 2 + ni) * 16 + nl;
            union { u64 d[2]; bf16x8 v; } bb;
            bb.d[0] = *(const u64*)(lb + ro + 144 * x);
            bb.d[1] = *(const u64*)(lb + ro + 144 * x + 8);
            acc[0 * 2 + ni] = __builtin_amdgcn_mfma_f32_16x16x32_bf16(af0, bb.v, acc[0 * 2 + ni], 0, 0, 0);
            acc[1 * 2 + ni] = __builtin_amdgcn_mfma_f32_16x16x32_bf16(af1, bb.v, acc[1 * 2 + ni], 0, 0, 0);
        }
    }
#pragma unroll
    for (int ni = 0; ni < 2; ++ni) {
        int x = (ntg * 2 + ni) * 16 + nl;
        if (x < 62) {
#pragma unroll
            for (int mi = 0; mi < 2; ++mi) {
                int oc0 = (mtg * 2 + mi) * 16 + quad * 4;
                f32x4 a = acc[mi * 2 + ni];
                u64 pk = pack4bf(fmaxf(a[0], 0.f), fmaxf(a[1], 0.f), fmaxf(a[2], 0.f), fmaxf(a[3], 0.f));
                *(u64*)(out + (((size_t)b * 46 + y) * 62 + x) * 64 + oc0) = pk;
            }
        }
    }
}

// ---------------- conv3: NHWC in [128][46][62][64] -> NCHW-flatten bf16 [b][64*660]. 3x3 s2.
// M=64 (4 mt), N=30 (2 nt), K=576 (18 chunks = tap-halves). Wave covers 2mt x 1nt.
__global__ __launch_bounds__(256) void k_conv3m(const unsigned short* __restrict__ in,
                                                const unsigned short* __restrict__ w3t,
                                                const float* __restrict__ bias,
                                                unsigned short* __restrict__ out) {
    int b = blockIdx.x, y = blockIdx.y;
    int tid = threadIdx.x;
    // 3 rows x 65 px, pixel stride 136 B (128 data + 8 pad)
    __shared__ __align__(16) unsigned short lds[3 * 65 * 68];
    char* lb = (char*)lds;
    const u64* in64 = (const u64*)in;
    size_t gbase = ((size_t)b * 46 + 2 * y) * 62 * 16;
    for (int u = tid; u < 2976; u += 256) {
        int r = u / 992, rem = u - r * 992;
        int p = rem >> 4, h = rem & 15;
        u64 v = in64[gbase + (size_t)r * 62 * 16 + p * 16 + h];
        *(u64*)(lb + r * 8840 + p * 136 + h * 8) = v;
    }
    __syncthreads();
    int wave = tid >> 6, lane = tid & 63;
    int quad = lane >> 4, nl = lane & 15;
    int mtg = wave & 1, nt = wave >> 1;
    f32x4 acc[2];
#pragma unroll
    for (int mi = 0; mi < 2; ++mi) {
        float4 bv = *(const float4*)(bias + (mtg * 2 + mi) * 16 + quad * 4);
        acc[mi][0] = bv.x; acc[mi][1] = bv.y; acc[mi][2] = bv.z; acc[mi][3] = bv.w;
    }
    int x = nt * 16 + nl;
#pragma unroll
    for (int ks = 0; ks < 18; ++ks) {
        const int pos = ks >> 1, half = ks & 1;
        const int r = pos / 3, kx = pos - r * 3;
        bf16x8 af0 = *(const bf16x8*)(w3t + ((mtg * 2 + 0) * 16 + nl) * 576 + ks * 32 + quad * 8);
        bf16x8 af1 = *(const bf16x8*)(w3t + ((mtg * 2 + 1) * 16 + nl) * 576 + ks * 32 + quad * 8);
        int ro = r * 8840 + 136 * kx + half * 64 + quad * 16;
        union { u64 d[2]; bf16x8 v; } bb;
        bb.d[0] = *(const u64*)(lb + ro + 272 * x);
        bb.d[1] = *(const u64*)(lb + ro + 272 * x + 8);
        acc[0] = __builtin_amdgcn_mfma_f32_16x16x32_bf16(af0, bb.v, acc[0], 0, 0, 0);
        acc[1] = __builtin_amdgcn_mfma_f32_16x16x32_bf16(af1, bb.v, acc[1], 0, 0, 0);
    }
    if (x < 30) {
#pragma unroll
        for (int mi = 0; mi < 2; ++mi) {
            int oc0 = (mtg * 2 + mi) * 16 + quad * 4;
#pragma unroll
            for (int r2 = 0; r2 < 4; ++r2)
                out[(size_t)b * 42240 + (oc0 + r2) * 660 + y * 30 + x] = f2bf(acc[mi][r2]);
        }
    }
}

// ---------------- fc1 as bf16 MFMA GEMM: C(128,256) = A(128,42240) @ W(256,42240)^T
__global__ __launch_bounds__(256) void k_fc1_mfma(const unsigned short* __restrict__ A,
                                                  const float* __restrict__ W,
                                                  float* __restrict__ part) {
    int kc = blockIdx.x;  // 0..65, 640 K each
    int nb = blockIdx.y;  // 0..3, 64 N each
    int wave = threadIdx.x >> 6, lane = threadIdx.x & 63;
    int m16 = lane & 15, quad = lane >> 4;
    int n = nb * 64 + wave * 16 + m16;
    const float* wrow = W + (size_t)n * 42240;
    const unsigned short* abase = A + (size_t)m16 * 42240;
    f32x4 acc[8] = {};
    int k0 = kc * 640 + quad * 8;
    for (int ks = 0; ks < 20; ++ks) {
        int k = k0 + ks * 32;
        const uint32_t* wp = (const uint32_t*)(wrow + k);
        uint32_t u0 = wp[0], u1 = wp[1], u2 = wp[2], u3 = wp[3];
        uint32_t u4 = wp[4], u5 = wp[5], u6 = wp[6], u7 = wp[7];
        union { uint32_t u[4]; bf16x8 v; } bf;
        bf.u[0] = (u0 >> 16) | (u1 & 0xffff0000u);
        bf.u[1] = (u2 >> 16) | (u3 & 0xffff0000u);
        bf.u[2] = (u4 >> 16) | (u5 & 0xffff0000u);
        bf.u[3] = (u6 >> 16) | (u7 & 0xffff0000u);
#pragma unroll
        for (int tm = 0; tm < 8; ++tm) {
            bf16x8 af = *(const bf16x8*)(abase + (size_t)tm * 16 * 42240 + k);
            acc[tm] = __builtin_amdgcn_mfma_f32_16x16x32_bf16(af, bf.v, acc[tm], 0, 0, 0);
        }
    }
    float* pb = part + ((size_t)kc * 128) * 256 + n;
#pragma unroll
    for (int tm = 0; tm < 8; ++tm) {
        int row = tm * 16 + quad * 4;
#pragma unroll
        for (int r = 0; r < 4; ++r) pb[(size_t)(row + r) * 256] = acc[tm][r];
    }
}

__global__ __launch_bounds__(256) void k_fc1c(const float* __restrict__ part,
                                              const float* __restrict__ bias,
                                              float* __restrict__ o) {
    int b = blockIdx.x, n = threadIdx.x;
    float s = bias[n];
    for (int kc = 0; kc < 66; ++kc) s += part[((size_t)kc * 128 + b) * 256 + n];
    o[b * 256 + n] = fmaxf(s, 0.f);
}

// ---------------- fc2 + lowd1 + lowd2 fused -> cnn_out2 (h0/c0 source)
__global__ __launch_bounds__(128) void k_head(const float* __restrict__ f1o,
                                              const float* __restrict__ w2, const float* __restrict__ b2,
                                              const float* __restrict__ lw1, const float* __restrict__ lb1,
                                              const float* __restrict__ lw2, const float* __restrict__ lb2,
                                              float* __restrict__ cnn2) {
    int b = blockIdx.x, n = threadIdx.x;
    __shared__ float xa[256];
    __shared__ float xb[128];
    __shared__ float xc[128];
    xa[n] = f1o[b * 256 + n];
    xa[n + 128] = f1o[b * 256 + 128 + n];
    __syncthreads();
    float acc = b2[n];
    for (int k = 0; k < 256; ++k) acc = fmaf(xa[k], w2[n * 256 + k], acc);
    xb[n] = acc;  // cnn_out1, no relu
    __syncthreads();
    acc = lb1[n];
    for (int k = 0; k < 128; ++k) acc = fmaf(xb[k], lw1[n * 128 + k], acc);
    xc[n] = fmaxf(acc, 0.f);
    __syncthreads();
    acc = lb2[n];
    for (int k = 0; k < 128; ++k) acc = fmaf(xc[k], lw2[n * 128 + k], acc);
    cnn2[b * 128 + n] = acc;  // [:,:64]=c0, [:,64:]=h0
}

// ---------------- action MLP: (128,8,2) -> (128,8,16)
__global__ __launch_bounds__(256) void k_act(const float* __restrict__ ain,
                                             const float* __restrict__ w1, const float* __restrict__ b1,
                                             const float* __restrict__ w2, const float* __restrict__ b2,
                                             float* __restrict__ abuf) {
    int idx = blockIdx.x * 256 + threadIdx.x;
    float x0 = ain[idx * 2], x1 = ain[idx * 2 + 1];
    float h1[16];
#pragma unroll
    for (int i = 0; i < 16; ++i)
        h1[i] = fmaxf(fmaf(x0, w1[i * 2], fmaf(x1, w1[i * 2 + 1], b1[i])), 0.f);
#pragma unroll
    for (int i = 0; i < 16; ++i) {
        float a = b2[i];
#pragma unroll
        for (int j = 0; j < 16; ++j) a = fmaf(h1[j], w2[i * 16 + j], a);
        abuf[idx * 16 + i] = a;
    }
}

// ---------------- LSTM: 8 layers x 8 steps, one sample per block
__global__ __launch_bounds__(256) void k_lstm(const float* __restrict__ abuf,
                                              const float* __restrict__ cnn2,
                                              const float* __restrict__ Wih0,
                                              const float* __restrict__ Wih,
                                              const float* __restrict__ Whh,
                                              const float* __restrict__ bih,
                                              const float* __restrict__ bhh,
                                              float* __restrict__ lout) {
    int b = blockIdx.x, tid = threadIdx.x, lane = tid & 63;
    __shared__ float xs[8][64];
    __shared__ float gbuf[256];
    for (int i = tid; i < 512; i += 256) {
        int t = i >> 6, k = i & 63;
        xs[t][k] = (k < 16) ? abuf[(b * 8 + t) * 16 + k] : 0.f;
    }
    __syncthreads();
    for (int l = 0; l < 8; ++l) {
        float wih[64], whh[64];
        if (l == 0) {
#pragma unroll
            for (int k = 0; k < 64; ++k) wih[k] = (k < 16) ? Wih0[tid * 16 + k] : 0.f;
        } else {
#pragma unroll
            for (int k = 0; k < 64; ++k) wih[k] = Wih[((l - 1) * 256 + tid) * 64 + k];
        }
#pragma unroll
        for (int k = 0; k < 64; ++k) whh[k] = Whh[(l * 256 + tid) * 64 + k];
        float biasv = bih[l * 256 + tid] + bhh[l * 256 + tid];
        float v_h = cnn2[b * 128 + 64 + lane];
        float v_c = cnn2[b * 128 + lane];
        for (int t = 0; t < 8; ++t) {
            float v_x = xs[t][lane];
            float a0 = biasv, a1 = 0.f, a2 = 0.f, a3 = 0.f;
#pragma unroll
            for (int k = 0; k < 64; k += 4) {
                a0 = fmaf(wih[k], bcastf(v_x, k), a0);
                a1 = fmaf(wih[k + 1], bcastf(v_x, k + 1), a1);
                a2 = fmaf(wih[k + 2], bcastf(v_x, k + 2), a2);
                a3 = fmaf(wih[k + 3], bcastf(v_x, k + 3), a3);
            }
#pragma unroll
            for (int k = 0; k < 64; k += 4) {
                a0 = fmaf(whh[k], bcastf(v_h, k), a0);
                a1 = fmaf(whh[k + 1], bcastf(v_h, k + 1), a1);
                a2 = fmaf(whh[k + 2], bcastf(v_h, k + 2), a2);
                a3 = fmaf(whh[k + 3], bcastf(v_h, k + 3), a3);
            }
            gbuf[tid] = (a0 + a1) + (a2 + a3);
            __syncthreads();
            float gi = gbuf[lane], gf = gbuf[64 + lane], gg = gbuf[128 + lane], go = gbuf[192 + lane];
            float cn = sigm(gf) * v_c + sigm(gi) * tanh_(gg);
            float hn = sigm(go) * tanh_(cn);
            v_c = cn;
            v_h = hn;
            if (tid < 64) xs[t][tid] = hn;
            __syncthreads();
        }
    }
    for (int i = tid; i < 512; i += 256) {
        int t = i >> 6, k = i & 63;
        lout[(b * 8 + t) * 64 + k] = xs[t][k];
    }
}

// ---------------- out MLP + rotation -> d_out (128,8,4)
__global__ __launch_bounds__(256) void k_out(const float* __restrict__ lout,
                                             const float* __restrict__ w1, const float* __restrict__ b1,
                                             const float* __restrict__ w2, const float* __restrict__ b2,
                                             const float* __restrict__ gt, float* __restrict__ out) {
    int idx = blockIdx.x * 256 + threadIdx.x;
    int b = idx >> 3;
    float x[64];
#pragma unroll
    for (int j = 0; j < 64; ++j) x[j] = lout[idx * 64 + j];
    float h[32];
#pragma unroll 8
    for (int i = 0; i < 32; ++i) {
        float a = b1[i];
#pragma unroll
        for (int j = 0; j < 64; ++j) a = fmaf(x[j], w1[i * 64 + j], a);
        h[i] = fmaxf(a, 0.f);
    }
    float mo[4];
#pragma unroll
    for (int i = 0; i < 4; ++i) {
        float a = b2[i];
#pragma unroll
        for (int j = 0; j < 32; ++j) a = fmaf(h[j], w2[i * 32 + j], a);
        mo[i] = a;
    }
    float yaw = gt[b * 48 + 5];
    float cy = cosf(yaw), sy = sinf(yaw);
    out[idx * 4 + 0] = fmaf(mo[0], cy, fmaf(mo[1], sy, gt[b * 48 + 1]));
    out[idx * 4 + 1] = fmaf(mo[0], -sy, fmaf(mo[1], cy, gt[b * 48 + 2]));
    out[idx * 4 + 2] = mo[2] + gt[b * 48 + 3];
    out[idx * 4 + 3] = mo[3];
}

extern "C" void kernel_launch(void* const* d_in, const int* in_sizes, int n_in,
                              void* d_out, int out_size, void* d_ws, size_t ws_size,
                              hipStream_t stream) {
    const float* img = (const float*)d_in[0];
    const float* ain = (const float*)d_in[1];
    const float* gt = (const float*)d_in[2];
    const float* c1w = (const float*)d_in[3];
    const float* c1b = (const float*)d_in[4];
    const float* c2w = (const float*)d_in[5];
    const float* c2b = (const float*)d_in[6];
    const float* c3w = (const float*)d_in[7];
    const float* c3b = (const float*)d_in[8];
    const float* f1w = (const float*)d_in[9];
    const float* f1b = (const float*)d_in[10];
    const float* f2w = (const float*)d_in[11];
    const float* f2b = (const float*)d_in[12];
    const float* l1w = (const float*)d_in[13];
    const float* l1b = (const float*)d_in[14];
    const float* l2w = (const float*)d_in[15];
    const float* l2b = (const float*)d_in[16];
    const float* a1w = (const float*)d_in[17];
    const float* a1b = (const float*)d_in[18];
    const float* a2w = (const float*)d_in[19];
    const float* a2b = (const float*)d_in[20];
    const float* wih0 = (const float*)d_in[21];
    const float* wih = (const float*)d_in[22];
    const float* whh = (const float*)d_in[23];
    const float* bihp = (const float*)d_in[24];
    const float* bhhp = (const float*)d_in[25];
    const float* o1w = (const float*)d_in[26];
    const float* o1b = (const float*)d_in[27];
    const float* o2w = (const float*)d_in[28];
    const float* o2b = (const float*)d_in[29];
    float* out = (float*)d_out;

    char* ws = (char*)d_ws;
    unsigned short* c1o = (unsigned short*)(ws);                 // NHWC 128*94*126*32 = 97,026,048 B
    unsigned short* c2o = (unsigned short*)(ws + 97026048);      // NHWC 128*46*62*64 = 46,727,168 B
    unsigned short* c3o = (unsigned short*)(ws + 143753216);     // flatten 10,813,440 B
    float* f1p = (float*)(ws + 154566656);                       // 8,650,752 B
    float* f1o = (float*)(ws + 163217408);
    float* cnn2 = (float*)(ws + 163348480);
    float* abuf = (float*)(ws + 163414016);
    float* lo = (float*)(ws + 163479552);
    unsigned short* w1t = (unsigned short*)(ws + 163741696);     // 8,192 B
    unsigned short* w2t = (unsigned short*)(ws + 163749888);     // 36,864 B
    unsigned short* w3t = (unsigned short*)(ws + 163786752);     // 73,728 B

    k_wprep<<<232, 256, 0, stream>>>(c1w, c2w, c3w, w1t, w2t, w3t);
    k_conv1m<<<dim3(128, 94), 256, 0, stream>>>(img, w1t, c1b, c1o);
    k_conv2m<<<dim3(128, 46), 256, 0, stream>>>(c1o, w2t, c2b, c2o);
    k_conv3m<<<dim3(128, 22), 256, 0, stream>>>(c2o, w3t, c3b, c3o);
    k_fc1_mfma<<<dim3(66, 4), 256, 0, stream>>>(c3o, f1w, f1p);
    k_fc1c<<<128, 256, 0, stream>>>(f1p, f1b, f1o);
    k_head<<<128, 128, 0, stream>>>(f1o, f2w, f2b, l1w, l1b, l2w, l2b, cnn2);
    k_act<<<4, 256, 0, stream>>>(ain, a1w, a1b, a2w, a2b, abuf);
    k_lstm<<<128, 256, 0, stream>>>(abuf, cnn2, wih0, wih, whh, bihp, bhhp, lo);
    k_out<<<4, 256, 0, stream>>>(lo, o1w, o1b, o2w, o2b, gt, out);
}

// Round 6
// 516.330 us; speedup vs baseline: 3.5075x; 1.0491x over previous
//
#include <hip/hip_runtime.h>
#include <cstdint>

#define DEV __device__ __forceinline__

typedef __attribute__((ext_vector_type(8))) short bf16x8;
typedef __attribute__((ext_vector_type(4))) float f32x4;
typedef __attribute__((ext_vector_type(2))) __fp16 h2t;
typedef unsigned long long u64;

DEV unsigned short f2bf(float f) {
    unsigned u = __float_as_uint(f);
    unsigned r = u + 0x7fffu + ((u >> 16) & 1u);
    return (unsigned short)(r >> 16);
}
DEV uint32_t pkh2(float a, float b) {
    h2t p = __builtin_amdgcn_cvt_pkrtz(a, b);
    union { h2t h; uint32_t u; } c;
    c.h = p;
    return c.u;
}
DEV float dot2(uint32_t w, uint32_t x, float acc) {
#if __has_builtin(__builtin_amdgcn_fdot2)
    union { uint32_t u; h2t h; } a, b;
    a.u = w; b.u = x;
    return __builtin_amdgcn_fdot2(a.h, b.h, acc, false);
#else
    union { uint32_t u; h2t h; } a, b;
    a.u = w; b.u = x;
    return acc + (float)a.h.x * (float)b.h.x + (float)a.h.y * (float)b.h.y;
#endif
}
DEV float sigm(float x) { return __builtin_amdgcn_rcpf(1.f + __expf(-x)); }
DEV float tanh_(float x) { return fmaf(2.f, sigm(2.f * x), -1.f); }
DEV uint32_t packpair(float h) {
    float hs = __int_as_float(__builtin_amdgcn_ds_swizzle(__float_as_int(h), 0x041F));
    return pkh2(h, hs);  // even lanes: (h_L, h_{L+1}) — only even lanes are read
}
DEV uint32_t comp4(uint4 v, int e) {
    return (e == 0) ? v.x : (e == 1) ? v.y : (e == 2) ? v.z : v.w;
}
DEV u64 pack4bf(float a, float b, float c, float d) {
    unsigned lo = (unsigned)f2bf(a) | ((unsigned)f2bf(b) << 16);
    unsigned hi = (unsigned)f2bf(c) | ((unsigned)f2bf(d) << 16);
    return (u64)lo | ((u64)hi << 32);
}

// ---------------- weight prep (bf16, K-chunk order)
__global__ __launch_bounds__(256) void k_wprep(const float* __restrict__ w1,
                                               const float* __restrict__ w2,
                                               const float* __restrict__ w3,
                                               unsigned short* __restrict__ w1t,
                                               unsigned short* __restrict__ w2t,
                                               unsigned short* __restrict__ w3t) {
    int i = blockIdx.x * 256 + threadIdx.x;
    if (i < 32 * 128) {
        int oc = i >> 7, k = i & 127;
        int tap = k >> 2, c = k & 3;
        w1t[i] = (tap < 25 && c < 3) ? f2bf(w1[oc * 75 + c * 25 + tap]) : (unsigned short)0;
    } else if (i < 32 * 128 + 64 * 288) {
        int j = i - 32 * 128;
        int oc = j / 288, k = j - oc * 288;
        int pos = k >> 5, c = k & 31;
        w2t[j] = f2bf(w2[oc * 288 + c * 9 + pos]);
    } else if (i < 32 * 128 + 64 * 288 + 64 * 576) {
        int j = i - 32 * 128 - 64 * 288;
        int oc = j / 576, k = j - oc * 576;
        int pos = k >> 6, c = k & 63;
        w3t[j] = f2bf(w3[oc * 576 + c * 9 + pos]);
    }
}

// ---------------- LSTM weight prep: f16 pairs, wpk[(l*64 + j)*64 + lane] = uint4
// j = g*16 + q; row r = g*64+lane; uint4 covers pairs p=4q..4q+3; pair p = k(2p,2p+1);
// k<64 -> Wih (layer0: k<16 from Wih0 else 0), k>=64 -> Whh[k-64]
__global__ __launch_bounds__(256) void k_wprep_lstm(const float* __restrict__ Wih0,
                                                    const float* __restrict__ Wih,
                                                    const float* __restrict__ Whh,
                                                    uint32_t* __restrict__ wpk) {
    int idx = blockIdx.x * 256 + threadIdx.x;  // 0..32767
    int lane = idx & 63;
    int j = (idx >> 6) & 63;
    int l = idx >> 12;
    int g = j >> 4, q = j & 15;
    int r = g * 64 + lane;
    uint32_t ov[4];
#pragma unroll
    for (int e = 0; e < 4; ++e) {
        int p = q * 4 + e;
        float w0, w1;
        if (p < 32) {
            int k0 = 2 * p;
            if (l == 0) {
                w0 = (k0 < 16) ? Wih0[r * 16 + k0] : 0.f;
                w1 = (k0 + 1 < 16) ? Wih0[r * 16 + k0 + 1] : 0.f;
            } else {
                const float* base = Wih + ((size_t)(l - 1) * 256 + r) * 64;
                w0 = base[k0];
                w1 = base[k0 + 1];
            }
        } else {
            int k0 = 2 * (p - 32);
            const float* base = Whh + ((size_t)l * 256 + r) * 64;
            w0 = base[k0];
            w1 = base[k0 + 1];
        }
        ov[e] = pkh2(w0, w1);
    }
    uint4 v;
    v.x = ov[0]; v.y = ov[1]; v.z = ov[2]; v.w = ov[3];
    ((uint4*)wpk)[idx] = v;
}

// ---------------- conv1: NCHW fp32 img -> NHWC c1o[b][y][x][32] bf16. 5x5 s2 ReLU.
__global__ __launch_bounds__(256) void k_conv1m(const float* __restrict__ img,
                                                const unsigned short* __restrict__ w1t,
                                                const float* __restrict__ bias,
                                                unsigned short* __restrict__ out) {
    int b = blockIdx.x, y = blockIdx.y;
    int tid = threadIdx.x;
    __shared__ __align__(16) unsigned short lds[7 * 1040];
    char* lb = (char*)lds;
    uint32_t* z32 = (uint32_t*)(lb + 5 * 2080);
    for (int u = tid; u < 1040; u += 256) z32[u] = 0;
    const float* ibase = img + (size_t)b * 3 * 192 * 256 + (size_t)(2 * y) * 256;
    for (int u = tid; u < 1280; u += 256) {
        int r = u >> 8, p = u & 255;
        const float* ip = ibase + r * 256 + p;
        float f0 = ip[0], f1 = ip[192 * 256], f2 = ip[2 * 192 * 256];
        uint32_t lo = (uint32_t)f2bf(f0) | ((uint32_t)f2bf(f1) << 16);
        uint32_t hi = (uint32_t)f2bf(f2);
        *(u64*)(lb + r * 2080 + p * 8) = (u64)lo | ((u64)hi << 32);
    }
    __syncthreads();
    int wave = tid >> 6, lane = tid & 63;
    int quad = lane >> 4, nl = lane & 15;
    int mt = wave & 1, ntg = wave >> 1;
    float4 bv = *(const float4*)(bias + mt * 16 + quad * 4);
    f32x4 acc[4];
#pragma unroll
    for (int q = 0; q < 4; ++q) { acc[q][0] = bv.x; acc[q][1] = bv.y; acc[q][2] = bv.z; acc[q][3] = bv.w; }
    const unsigned short* wbase = w1t + (mt * 16 + nl) * 128 + quad * 8;
#pragma unroll
    for (int ks = 0; ks < 4; ++ks) {
        bf16x8 af = *(const bf16x8*)(wbase + ks * 32);
        int t0 = ks * 8 + quad * 2;
        int r0 = t0 / 5, kx0 = t0 - r0 * 5;
        int t1 = t0 + 1;
        int r1 = t1 / 5, kx1 = t1 - r1 * 5;
        int ro0 = r0 * 2080 + kx0 * 8;
        int ro1 = r1 * 2080 + kx1 * 8;
#pragma unroll
        for (int q = 0; q < 4; ++q) {
            int x = (ntg * 4 + q) * 16 + nl;
            union { u64 d[2]; bf16x8 v; } bb;
            bb.d[0] = *(const u64*)(lb + ro0 + x * 16);
            bb.d[1] = *(const u64*)(lb + ro1 + x * 16);
            acc[q] = __builtin_amdgcn_mfma_f32_16x16x32_bf16(af, bb.v, acc[q], 0, 0, 0);
        }
    }
    int oc0 = mt * 16 + quad * 4;
#pragma unroll
    for (int q = 0; q < 4; ++q) {
        int x = (ntg * 4 + q) * 16 + nl;
        if (x < 126) {
            u64 pk = pack4bf(fmaxf(acc[q][0], 0.f), fmaxf(acc[q][1], 0.f),
                             fmaxf(acc[q][2], 0.f), fmaxf(acc[q][3], 0.f));
            *(u64*)(out + (((size_t)b * 94 + y) * 126 + x) * 32 + oc0) = pk;
        }
    }
}

// ---------------- conv2: NHWC in -> NHWC out [128][46][62][64]. 3x3 s2 ReLU.
__global__ __launch_bounds__(256) void k_conv2m(const unsigned short* __restrict__ in,
                                                const unsigned short* __restrict__ w2t,
                                                const float* __restrict__ bias,
                                                unsigned short* __restrict__ out) {
    int b = blockIdx.x, y = blockIdx.y;
    int tid = threadIdx.x;
    __shared__ __align__(16) unsigned short lds[3 * 130 * 36];
    char* lb = (char*)lds;
    const u64* in64 = (const u64*)in;
    size_t gbase = ((size_t)b * 94 + 2 * y) * 126 * 8;
    for (int u = tid; u < 3024; u += 256) {
        int r = u / 1008, rem = u - r * 1008;
        int p = rem >> 3, h = rem & 7;
        u64 v = in64[gbase + (size_t)r * 126 * 8 + p * 8 + h];
        *(u64*)(lb + r * 9360 + p * 72 + h * 8) = v;
    }
    __syncthreads();
    int wave = tid >> 6, lane = tid & 63;
    int quad = lane >> 4, nl = lane & 15;
    int mtg = wave & 1, ntg = wave >> 1;
    f32x4 acc[4];
#pragma unroll
    for (int mi = 0; mi < 2; ++mi) {
        float4 bv = *(const float4*)(bias + (mtg * 2 + mi) * 16 + quad * 4);
#pragma unroll
        for (int ni = 0; ni < 2; ++ni) {
            acc[mi * 2 + ni][0] = bv.x; acc[mi * 2 + ni][1] = bv.y;
            acc[mi * 2 + ni][2] = bv.z; acc[mi * 2 + ni][3] = bv.w;
        }
    }
#pragma unroll
    for (int ks = 0; ks < 9; ++ks) {
        const int r = ks / 3, kx = ks - r * 3;
        bf16x8 af0 = *(const bf16x8*)(w2t + ((mtg * 2 + 0) * 16 + nl) * 288 + ks * 32 + quad * 8);
        bf16x8 af1 = *(const bf16x8*)(w2t + ((mtg * 2 + 1) * 16 + nl) * 288 + ks * 32 + quad * 8);
        int ro = r * 9360 + 72 * kx + quad * 16;
#pragma unroll
        for (int ni = 0; ni < 2; ++ni) {
            int x = (ntg * 2 + ni) * 16 + nl;
            union { u64 d[2]; bf16x8 v; } bb;
            bb.d[0] = *(const u64*)(lb + ro + 144 * x);
            bb.d[1] = *(const u64*)(lb + ro + 144 * x + 8);
            acc[0 * 2 + ni] = __builtin_amdgcn_mfma_f32_16x16x32_bf16(af0, bb.v, acc[0 * 2 + ni], 0, 0, 0);
            acc[1 * 2 + ni] = __builtin_amdgcn_mfma_f32_16x16x32_bf16(af1, bb.v, acc[1 * 2 + ni], 0, 0, 0);
        }
    }
#pragma unroll
    for (int ni = 0; ni < 2; ++ni) {
        int x = (ntg * 2 + ni) * 16 + nl;
        if (x < 62) {
#pragma unroll
            for (int mi = 0; mi < 2; ++mi) {
                int oc0 = (mtg * 2 + mi) * 16 + quad * 4;
                f32x4 a = acc[mi * 2 + ni];
                u64 pk = pack4bf(fmaxf(a[0], 0.f), fmaxf(a[1], 0.f), fmaxf(a[2], 0.f), fmaxf(a[3], 0.f));
                *(u64*)(out + (((size_t)b * 46 + y) * 62 + x) * 64 + oc0) = pk;
            }
        }
    }
}

// ---------------- conv3: NHWC in -> NCHW-flatten bf16 [b][64*660]. 3x3 s2.
__global__ __launch_bounds__(256) void k_conv3m(const unsigned short* __restrict__ in,
                                                const unsigned short* __restrict__ w3t,
                                                const float* __restrict__ bias,
                                                unsigned short* __restrict__ out) {
    int b = blockIdx.x, y = blockIdx.y;
    int tid = threadIdx.x;
    __shared__ __align__(16) unsigned short lds[3 * 65 * 68];
    char* lb = (char*)lds;
    const u64* in64 = (const u64*)in;
    size_t gbase = ((size_t)b * 46 + 2 * y) * 62 * 16;
    for (int u = tid; u < 2976; u += 256) {
        int r = u / 992, rem = u - r * 992;
        int p = rem >> 4, h = rem & 15;
        u64 v = in64[gbase + (size_t)r * 62 * 16 + p * 16 + h];
        *(u64*)(lb + r * 8840 + p * 136 + h * 8) = v;
    }
    __syncthreads();
    int wave = tid >> 6, lane = tid & 63;
    int quad = lane >> 4, nl = lane & 15;
    int mtg = wave & 1, nt = wave >> 1;
    f32x4 acc[2];
#pragma unroll
    for (int mi = 0; mi < 2; ++mi) {
        float4 bv = *(const float4*)(bias + (mtg * 2 + mi) * 16 + quad * 4);
        acc[mi][0] = bv.x; acc[mi][1] = bv.y; acc[mi][2] = bv.z; acc[mi][3] = bv.w;
    }
    int x = nt * 16 + nl;
#pragma unroll
    for (int ks = 0; ks < 18; ++ks) {
        const int pos = ks >> 1, half = ks & 1;
        const int r = pos / 3, kx = pos - r * 3;
        bf16x8 af0 = *(const bf16x8*)(w3t + ((mtg * 2 + 0) * 16 + nl) * 576 + ks * 32 + quad * 8);
        bf16x8 af1 = *(const bf16x8*)(w3t + ((mtg * 2 + 1) * 16 + nl) * 576 + ks * 32 + quad * 8);
        int ro = r * 8840 + 136 * kx + half * 64 + quad * 16;
        union { u64 d[2]; bf16x8 v; } bb;
        bb.d[0] = *(const u64*)(lb + ro + 272 * x);
        bb.d[1] = *(const u64*)(lb + ro + 272 * x + 8);
        acc[0] = __builtin_amdgcn_mfma_f32_16x16x32_bf16(af0, bb.v, acc[0], 0, 0, 0);
        acc[1] = __builtin_amdgcn_mfma_f32_16x16x32_bf16(af1, bb.v, acc[1], 0, 0, 0);
    }
    if (x < 30) {
#pragma unroll
        for (int mi = 0; mi < 2; ++mi) {
            int oc0 = (mtg * 2 + mi) * 16 + quad * 4;
#pragma unroll
            for (int r2 = 0; r2 < 4; ++r2)
                out[(size_t)b * 42240 + (oc0 + r2) * 660 + y * 30 + x] = f2bf(acc[mi][r2]);
        }
    }
}

// ---------------- fc1 as bf16 MFMA GEMM
__global__ __launch_bounds__(256) void k_fc1_mfma(const unsigned short* __restrict__ A,
                                                  const float* __restrict__ W,
                                                  float* __restrict__ part) {
    int kc = blockIdx.x;
    int nb = blockIdx.y;
    int wave = threadIdx.x >> 6, lane = threadIdx.x & 63;
    int m16 = lane & 15, quad = lane >> 4;
    int n = nb * 64 + wave * 16 + m16;
    const float* wrow = W + (size_t)n * 42240;
    const unsigned short* abase = A + (size_t)m16 * 42240;
    f32x4 acc[8] = {};
    int k0 = kc * 640 + quad * 8;
    for (int ks = 0; ks < 20; ++ks) {
        int k = k0 + ks * 32;
        const uint32_t* wp = (const uint32_t*)(wrow + k);
        uint32_t u0 = wp[0], u1 = wp[1], u2 = wp[2], u3 = wp[3];
        uint32_t u4 = wp[4], u5 = wp[5], u6 = wp[6], u7 = wp[7];
        union { uint32_t u[4]; bf16x8 v; } bf;
        bf.u[0] = (u0 >> 16) | (u1 & 0xffff0000u);
        bf.u[1] = (u2 >> 16) | (u3 & 0xffff0000u);
        bf.u[2] = (u4 >> 16) | (u5 & 0xffff0000u);
        bf.u[3] = (u6 >> 16) | (u7 & 0xffff0000u);
#pragma unroll
        for (int tm = 0; tm < 8; ++tm) {
            bf16x8 af = *(const bf16x8*)(abase + (size_t)tm * 16 * 42240 + k);
            acc[tm] = __builtin_amdgcn_mfma_f32_16x16x32_bf16(af, bf.v, acc[tm], 0, 0, 0);
        }
    }
    float* pb = part + ((size_t)kc * 128) * 256 + n;
#pragma unroll
    for (int tm = 0; tm < 8; ++tm) {
        int row = tm * 16 + quad * 4;
#pragma unroll
        for (int r = 0; r < 4; ++r) pb[(size_t)(row + r) * 256] = acc[tm][r];
    }
}

__global__ __launch_bounds__(256) void k_fc1c(const float* __restrict__ part,
                                              const float* __restrict__ bias,
                                              float* __restrict__ o) {
    int b = blockIdx.x, n = threadIdx.x;
    float s = bias[n];
    for (int kc = 0; kc < 66; ++kc) s += part[((size_t)kc * 128 + b) * 256 + n];
    o[b * 256 + n] = fmaxf(s, 0.f);
}

// ---------------- fc2 + lowd1 + lowd2 fused -> cnn_out2
__global__ __launch_bounds__(128) void k_head(const float* __restrict__ f1o,
                                              const float* __restrict__ w2, const float* __restrict__ b2,
                                              const float* __restrict__ lw1, const float* __restrict__ lb1,
                                              const float* __restrict__ lw2, const float* __restrict__ lb2,
                                              float* __restrict__ cnn2) {
    int b = blockIdx.x, n = threadIdx.x;
    __shared__ float xa[256];
    __shared__ float xb[128];
    __shared__ float xc[128];
    xa[n] = f1o[b * 256 + n];
    xa[n + 128] = f1o[b * 256 + 128 + n];
    __syncthreads();
    float acc = b2[n];
    for (int k = 0; k < 256; ++k) acc = fmaf(xa[k], w2[n * 256 + k], acc);
    xb[n] = acc;
    __syncthreads();
    acc = lb1[n];
    for (int k = 0; k < 128; ++k) acc = fmaf(xb[k], lw1[n * 128 + k], acc);
    xc[n] = fmaxf(acc, 0.f);
    __syncthreads();
    acc = lb2[n];
    for (int k = 0; k < 128; ++k) acc = fmaf(xc[k], lw2[n * 128 + k], acc);
    cnn2[b * 128 + n] = acc;
}

// ---------------- action MLP
__global__ __launch_bounds__(256) void k_act(const float* __restrict__ ain,
                                             const float* __restrict__ w1, const float* __restrict__ b1,
                                             const float* __restrict__ w2, const float* __restrict__ b2,
                                             float* __restrict__ abuf) {
    int idx = blockIdx.x * 256 + threadIdx.x;
    float x0 = ain[idx * 2], x1 = ain[idx * 2 + 1];
    float h1[16];
#pragma unroll
    for (int i = 0; i < 16; ++i)
        h1[i] = fmaxf(fmaf(x0, w1[i * 2], fmaf(x1, w1[i * 2 + 1], b1[i])), 0.f);
#pragma unroll
    for (int i = 0; i < 16; ++i) {
        float a = b2[i];
#pragma unroll
        for (int j = 0; j < 16; ++j) a = fmaf(h1[j], w2[i * 16 + j], a);
        abuf[idx * 16 + i] = a;
    }
}

// ---------------- LSTM v2: one wave per sample, wave-synchronous, f16 dot2.
// Lane = hidden unit; lane owns gate rows {lane, 64+lane, 128+lane, 192+lane}.
// Weights: wpk[(l*64 + g*16 + q)*64 + lane] uint4 (pairs 4q..4q+3 of row g*64+lane).
// x/h broadcast via readlane of f16-pair registers (even lanes hold pairs).
__global__ __launch_bounds__(64, 1) void k_lstm(const float* __restrict__ abuf,
                                                const float* __restrict__ cnn2,
                                                const uint32_t* __restrict__ wpk,
                                                const float* __restrict__ bih,
                                                const float* __restrict__ bhh,
                                                float* __restrict__ lout) {
    int b = blockIdx.x, lane = threadIdx.x;
    uint32_t xpk[8];
#pragma unroll
    for (int t = 0; t < 8; ++t) {
        float x0 = 0.f, x1 = 0.f;
        if (lane < 8) {
            const float* ap = abuf + (b * 8 + t) * 16 + 2 * lane;
            x0 = ap[0];
            x1 = ap[1];
        }
        xpk[t] = pkh2(x0, x1);
    }
    float h0 = cnn2[b * 128 + 64 + lane];
    float c0 = cnn2[b * 128 + lane];
    const uint4* wbase = (const uint4*)wpk;
    for (int l = 0; l < 8; ++l) {
        uint4 wreg[64];
        const uint4* wp = wbase + (size_t)l * 4096 + lane;
#pragma unroll
        for (int j = 0; j < 64; ++j) wreg[j] = wp[j * 64];
        float bias0 = bih[l * 256 + lane] + bhh[l * 256 + lane];
        float bias1 = bih[l * 256 + 64 + lane] + bhh[l * 256 + 64 + lane];
        float bias2 = bih[l * 256 + 128 + lane] + bhh[l * 256 + 128 + lane];
        float bias3 = bih[l * 256 + 192 + lane] + bhh[l * 256 + 192 + lane];
        float h = h0, c = c0;
        uint32_t hpk = packpair(h);
#pragma unroll
        for (int t = 0; t < 8; ++t) {
            float a0 = bias0, a1 = bias1, a2 = bias2, a3 = bias3;
#pragma unroll
            for (int p = 0; p < 32; ++p) {
                uint32_t bx = (uint32_t)__builtin_amdgcn_readlane((int)xpk[t], p);
                int q = p >> 2, e = p & 3;
                a0 = dot2(comp4(wreg[q], e), bx, a0);
                a1 = dot2(comp4(wreg[16 + q], e), bx, a1);
                a2 = dot2(comp4(wreg[32 + q], e), bx, a2);
                a3 = dot2(comp4(wreg[48 + q], e), bx, a3);
            }
#pragma unroll
            for (int m = 0; m < 32; ++m) {
                uint32_t bh = (uint32_t)__builtin_amdgcn_readlane((int)hpk, 2 * m);
                int q = 8 + (m >> 2), e = m & 3;
                a0 = dot2(comp4(wreg[q], e), bh, a0);
                a1 = dot2(comp4(wreg[16 + q], e), bh, a1);
                a2 = dot2(comp4(wreg[32 + q], e), bh, a2);
                a3 = dot2(comp4(wreg[48 + q], e), bh, a3);
            }
            float gi = sigm(a0), gf = sigm(a1), gv = tanh_(a2), go = sigm(a3);
            c = gf * c + gi * gv;
            h = go * tanh_(c);
            hpk = packpair(h);
            xpk[t] = hpk;  // becomes x_t of next layer
            if (l == 7) lout[(b * 8 + t) * 64 + lane] = h;
        }
    }
}

// ---------------- out MLP + rotation -> d_out (128,8,4)
__global__ __launch_bounds__(256) void k_out(const float* __restrict__ lout,
                                             const float* __restrict__ w1, const float* __restrict__ b1,
                                             const float* __restrict__ w2, const float* __restrict__ b2,
                                             const float* __restrict__ gt, float* __restrict__ out) {
    int idx = blockIdx.x * 256 + threadIdx.x;
    int b = idx >> 3;
    float x[64];
#pragma unroll
    for (int j = 0; j < 64; ++j) x[j] = lout[idx * 64 + j];
    float h[32];
#pragma unroll 8
    for (int i = 0; i < 32; ++i) {
        float a = b1[i];
#pragma unroll
        for (int j = 0; j < 64; ++j) a = fmaf(x[j], w1[i * 64 + j], a);
        h[i] = fmaxf(a, 0.f);
    }
    float mo[4];
#pragma unroll
    for (int i = 0; i < 4; ++i) {
        float a = b2[i];
#pragma unroll
        for (int j = 0; j < 32; ++j) a = fmaf(h[j], w2[i * 32 + j], a);
        mo[i] = a;
    }
    float yaw = gt[b * 48 + 5];
    float cy = cosf(yaw), sy = sinf(yaw);
    out[idx * 4 + 0] = fmaf(mo[0], cy, fmaf(mo[1], sy, gt[b * 48 + 1]));
    out[idx * 4 + 1] = fmaf(mo[0], -sy, fmaf(mo[1], cy, gt[b * 48 + 2]));
    out[idx * 4 + 2] = mo[2] + gt[b * 48 + 3];
    out[idx * 4 + 3] = mo[3];
}

extern "C" void kernel_launch(void* const* d_in, const int* in_sizes, int n_in,
                              void* d_out, int out_size, void* d_ws, size_t ws_size,
                              hipStream_t stream) {
    const float* img = (const float*)d_in[0];
    const float* ain = (const float*)d_in[1];
    const float* gt = (const float*)d_in[2];
    const float* c1w = (const float*)d_in[3];
    const float* c1b = (const float*)d_in[4];
    const float* c2w = (const float*)d_in[5];
    const float* c2b = (const float*)d_in[6];
    const float* c3w = (const float*)d_in[7];
    const float* c3b = (const float*)d_in[8];
    const float* f1w = (const float*)d_in[9];
    const float* f1b = (const float*)d_in[10];
    const float* f2w = (const float*)d_in[11];
    const float* f2b = (const float*)d_in[12];
    const float* l1w = (const float*)d_in[13];
    const float* l1b = (const float*)d_in[14];
    const float* l2w = (const float*)d_in[15];
    const float* l2b = (const float*)d_in[16];
    const float* a1w = (const float*)d_in[17];
    const float* a1b = (const float*)d_in[18];
    const float* a2w = (const float*)d_in[19];
    const float* a2b = (const float*)d_in[20];
    const float* wih0 = (const float*)d_in[21];
    const float* wih = (const float*)d_in[22];
    const float* whh = (const float*)d_in[23];
    const float* bihp = (const float*)d_in[24];
    const float* bhhp = (const float*)d_in[25];
    const float* o1w = (const float*)d_in[26];
    const float* o1b = (const float*)d_in[27];
    const float* o2w = (const float*)d_in[28];
    const float* o2b = (const float*)d_in[29];
    float* out = (float*)d_out;

    char* ws = (char*)d_ws;
    unsigned short* c1o = (unsigned short*)(ws);                 // 97,026,048 B
    unsigned short* c2o = (unsigned short*)(ws + 97026048);      // 46,727,168 B
    unsigned short* c3o = (unsigned short*)(ws + 143753216);     // 10,813,440 B
    float* f1p = (float*)(ws + 154566656);                       // 8,650,752 B
    float* f1o = (float*)(ws + 163217408);
    float* cnn2 = (float*)(ws + 163348480);
    float* abuf = (float*)(ws + 163414016);
    float* lo = (float*)(ws + 163479552);
    unsigned short* w1t = (unsigned short*)(ws + 163741696);     // 8,192 B
    unsigned short* w2t = (unsigned short*)(ws + 163749888);     // 36,864 B
    unsigned short* w3t = (unsigned short*)(ws + 163786752);     // 73,728 B
    uint32_t* wpk = (uint32_t*)(ws + 163860480);                 // 524,288 B

    k_wprep<<<232, 256, 0, stream>>>(c1w, c2w, c3w, w1t, w2t, w3t);
    k_wprep_lstm<<<128, 256, 0, stream>>>(wih0, wih, whh, wpk);
    k_conv1m<<<dim3(128, 94), 256, 0, stream>>>(img, w1t, c1b, c1o);
    k_conv2m<<<dim3(128, 46), 256, 0, stream>>>(c1o, w2t, c2b, c2o);
    k_conv3m<<<dim3(128, 22), 256, 0, stream>>>(c2o, w3t, c3b, c3o);
    k_fc1_mfma<<<dim3(66, 4), 256, 0, stream>>>(c3o, f1w, f1p);
    k_fc1c<<<128, 256, 0, stream>>>(f1p, f1b, f1o);
    k_head<<<128, 128, 0, stream>>>(f1o, f2w, f2b, l1w, l1b, l2w, l2b, cnn2);
    k_act<<<4, 256, 0, stream>>>(ain, a1w, a1b, a2w, a2b, abuf);
    k_lstm<<<128, 64, 0, stream>>>(abuf, cnn2, wpk, bihp, bhhp, lo);
    k_out<<<4, 256, 0, stream>>>(lo, o1w, o1b, o2w, o2b, gt, out);
}

// Round 7
// 495.619 us; speedup vs baseline: 3.6541x; 1.0418x over previous
//
#include <hip/hip_runtime.h>
#include <cstdint>

#define DEV __device__ __forceinline__

typedef __attribute__((ext_vector_type(8))) short bf16x8;
typedef __attribute__((ext_vector_type(4))) float f32x4;
typedef __attribute__((ext_vector_type(2))) __fp16 h2t;
typedef unsigned long long u64;

DEV unsigned short f2bf(float f) {
    unsigned u = __float_as_uint(f);
    unsigned r = u + 0x7fffu + ((u >> 16) & 1u);
    return (unsigned short)(r >> 16);
}
DEV uint32_t pkh2(float a, float b) {
    h2t p = __builtin_amdgcn_cvt_pkrtz(a, b);
    union { h2t h; uint32_t u; } c;
    c.h = p;
    return c.u;
}
DEV float dot2(uint32_t w, uint32_t x, float acc) {
    union { uint32_t u; h2t h; } a, b;
    a.u = w; b.u = x;
    return __builtin_amdgcn_fdot2(a.h, b.h, acc, false);
}
DEV float sigm(float x) { return __builtin_amdgcn_rcpf(1.f + __expf(-x)); }
DEV float tanh_(float x) { return fmaf(2.f, sigm(2.f * x), -1.f); }
DEV uint32_t packpair(float h) {
    float hs = __int_as_float(__builtin_amdgcn_ds_swizzle(__float_as_int(h), 0x041F));
    return pkh2(h, hs);
}
DEV uint32_t comp4(uint4 v, int e) {
    return (e == 0) ? v.x : (e == 1) ? v.y : (e == 2) ? v.z : v.w;
}
DEV u64 pack4bf(float a, float b, float c, float d) {
    unsigned lo = (unsigned)f2bf(a) | ((unsigned)f2bf(b) << 16);
    unsigned hi = (unsigned)f2bf(c) | ((unsigned)f2bf(d) << 16);
    return (u64)lo | ((u64)hi << 32);
}

// ---------------- weight prep (bf16, K-chunk order)
// conv1: w1t[oc][k], k = cc*8 + u*4 + c; chunk cc<15: taps (r=cc/3, kx=2*(cc%3)+u);
//        kx=5 / cc=15 / c=3 are phantom slots with ZERO weight (data read is garbage but finite).
// w2t[64][288]: k = tap*32 + c; w3t[64][576]: k = tap*64 + c
__global__ __launch_bounds__(256) void k_wprep(const float* __restrict__ w1,
                                               const float* __restrict__ w2,
                                               const float* __restrict__ w3,
                                               unsigned short* __restrict__ w1t,
                                               unsigned short* __restrict__ w2t,
                                               unsigned short* __restrict__ w3t) {
    int i = blockIdx.x * 256 + threadIdx.x;
    if (i < 32 * 128) {
        int oc = i >> 7, k = i & 127;
        int cc = k >> 3, u = (k >> 2) & 1, c = k & 3;
        int r = cc / 3, kx = 2 * (cc - 3 * r) + u;
        w1t[i] = (cc < 15 && kx < 5 && c < 3) ? f2bf(w1[oc * 75 + c * 25 + r * 5 + kx])
                                              : (unsigned short)0;
    } else if (i < 32 * 128 + 64 * 288) {
        int j = i - 32 * 128;
        int oc = j / 288, k = j - oc * 288;
        int pos = k >> 5, c = k & 31;
        w2t[j] = f2bf(w2[oc * 288 + c * 9 + pos]);
    } else if (i < 32 * 128 + 64 * 288 + 64 * 576) {
        int j = i - 32 * 128 - 64 * 288;
        int oc = j / 576, k = j - oc * 576;
        int pos = k >> 6, c = k & 63;
        w3t[j] = f2bf(w3[oc * 576 + c * 9 + pos]);
    }
}

// ---------------- LSTM weight prep: f16 pairs (see k_lstm)
__global__ __launch_bounds__(256) void k_wprep_lstm(const float* __restrict__ Wih0,
                                                    const float* __restrict__ Wih,
                                                    const float* __restrict__ Whh,
                                                    uint32_t* __restrict__ wpk) {
    int idx = blockIdx.x * 256 + threadIdx.x;  // 0..32767
    int lane = idx & 63;
    int j = (idx >> 6) & 63;
    int l = idx >> 12;
    int g = j >> 4, q = j & 15;
    int r = g * 64 + lane;
    uint32_t ov[4];
#pragma unroll
    for (int e = 0; e < 4; ++e) {
        int p = q * 4 + e;
        float w0, w1;
        if (p < 32) {
            int k0 = 2 * p;
            if (l == 0) {
                w0 = (k0 < 16) ? Wih0[r * 16 + k0] : 0.f;
                w1 = (k0 + 1 < 16) ? Wih0[r * 16 + k0 + 1] : 0.f;
            } else {
                const float* base = Wih + ((size_t)(l - 1) * 256 + r) * 64;
                w0 = base[k0];
                w1 = base[k0 + 1];
            }
        } else {
            int k0 = 2 * (p - 32);
            const float* base = Whh + ((size_t)l * 256 + r) * 64;
            w0 = base[k0];
            w1 = base[k0 + 1];
        }
        ov[e] = pkh2(w0, w1);
    }
    uint4 v;
    v.x = ov[0]; v.y = ov[1]; v.z = ov[2]; v.w = ov[3];
    ((uint4*)wpk)[idx] = v;
}

// ---------------- conv1 v2: 4 output rows/block, wave=row, b128 frags, 2 MFMA per frag.
// NCHW fp32 img -> NHWC c1o[b][y][x][32] bf16. 5x5 s2 ReLU.
__global__ __launch_bounds__(256) void k_conv1m(const float* __restrict__ img,
                                                const unsigned short* __restrict__ w1t,
                                                const float* __restrict__ bias,
                                                unsigned short* __restrict__ out) {
    int b = blockIdx.x, y0 = blockIdx.y * 4;
    int tid = threadIdx.x;
    __shared__ __align__(16) unsigned short lds[12 * 1040];  // 12 rows x 260 px x 4ch, 24960 B
    char* lb = (char*)lds;
    const float* ib = img + (size_t)b * 3 * 192 * 256;
#pragma unroll
    for (int r = 0; r < 12; ++r) {
        if (r < 11) {
            int row = 2 * y0 + r;
            if (row > 191) row = 191;
            const float* ip = ib + row * 256 + tid;
            float f0 = ip[0], f1 = ip[192 * 256], f2 = ip[2 * 192 * 256];
            uint32_t lo = (uint32_t)f2bf(f0) | ((uint32_t)f2bf(f1) << 16);
            *(u64*)(lb + r * 2080 + tid * 8) = (u64)lo | ((u64)f2bf(f2) << 32);
        } else {
            *(u64*)(lb + 11 * 2080 + tid * 8) = 0ull;  // phantom chunk for ly=3 lands here
        }
    }
    __syncthreads();
    int wave = tid >> 6, lane = tid & 63;
    int quad = lane >> 4, nl = lane & 15;
    int ly = wave;  // output row within block
    float4 bv0 = *(const float4*)(bias + quad * 4);
    float4 bv1 = *(const float4*)(bias + 16 + quad * 4);
    f32x4 acc[8][2];
#pragma unroll
    for (int nt = 0; nt < 8; ++nt) {
        acc[nt][0][0] = bv0.x; acc[nt][0][1] = bv0.y; acc[nt][0][2] = bv0.z; acc[nt][0][3] = bv0.w;
        acc[nt][1][0] = bv1.x; acc[nt][1][1] = bv1.y; acc[nt][1][2] = bv1.z; acc[nt][1][3] = bv1.w;
    }
#pragma unroll
    for (int ks = 0; ks < 4; ++ks) {
        int cc = ks * 4 + quad;
        int r = cc / 3, kxp = cc - 3 * r;  // cc=15 -> r=5,kxp=0 (zero weights)
        int rb = (2 * ly + r) * 2080 + kxp * 16 + nl * 16;
        bf16x8 af0 = *(const bf16x8*)(w1t + (nl) * 128 + ks * 32 + quad * 8);
        bf16x8 af1 = *(const bf16x8*)(w1t + (16 + nl) * 128 + ks * 32 + quad * 8);
#pragma unroll
        for (int nt = 0; nt < 8; ++nt) {
            bf16x8 bv = *(const bf16x8*)(lb + rb + nt * 256);
            acc[nt][0] = __builtin_amdgcn_mfma_f32_16x16x32_bf16(af0, bv, acc[nt][0], 0, 0, 0);
            acc[nt][1] = __builtin_amdgcn_mfma_f32_16x16x32_bf16(af1, bv, acc[nt][1], 0, 0, 0);
        }
    }
    int y = y0 + ly;
    if (y < 94) {
#pragma unroll
        for (int nt = 0; nt < 8; ++nt) {
            int x = nt * 16 + nl;
            if (x < 126) {
#pragma unroll
                for (int mi = 0; mi < 2; ++mi) {
                    f32x4 a = acc[nt][mi];
                    u64 pk = pack4bf(fmaxf(a[0], 0.f), fmaxf(a[1], 0.f),
                                     fmaxf(a[2], 0.f), fmaxf(a[3], 0.f));
                    *(u64*)(out + (((size_t)b * 94 + y) * 126 + x) * 32 + mi * 16 + quad * 4) = pk;
                }
            }
        }
    }
}

// ---------------- conv2: NHWC in -> NHWC out [128][46][62][64]. 3x3 s2 ReLU.
__global__ __launch_bounds__(256) void k_conv2m(const unsigned short* __restrict__ in,
                                                const unsigned short* __restrict__ w2t,
                                                const float* __restrict__ bias,
                                                unsigned short* __restrict__ out) {
    int b = blockIdx.x, y = blockIdx.y;
    int tid = threadIdx.x;
    __shared__ __align__(16) unsigned short lds[3 * 130 * 36];
    char* lb = (char*)lds;
    const u64* in64 = (const u64*)in;
    size_t gbase = ((size_t)b * 94 + 2 * y) * 126 * 8;
    for (int u = tid; u < 3024; u += 256) {
        int r = u / 1008, rem = u - r * 1008;
        int p = rem >> 3, h = rem & 7;
        u64 v = in64[gbase + (size_t)r * 126 * 8 + p * 8 + h];
        *(u64*)(lb + r * 9360 + p * 72 + h * 8) = v;
    }
    __syncthreads();
    int wave = tid >> 6, lane = tid & 63;
    int quad = lane >> 4, nl = lane & 15;
    int mtg = wave & 1, ntg = wave >> 1;
    f32x4 acc[4];
#pragma unroll
    for (int mi = 0; mi < 2; ++mi) {
        float4 bv = *(const float4*)(bias + (mtg * 2 + mi) * 16 + quad * 4);
#pragma unroll
        for (int ni = 0; ni < 2; ++ni) {
            acc[mi * 2 + ni][0] = bv.x; acc[mi * 2 + ni][1] = bv.y;
            acc[mi * 2 + ni][2] = bv.z; acc[mi * 2 + ni][3] = bv.w;
        }
    }
#pragma unroll
    for (int ks = 0; ks < 9; ++ks) {
        const int r = ks / 3, kx = ks - r * 3;
        bf16x8 af0 = *(const bf16x8*)(w2t + ((mtg * 2 + 0) * 16 + nl) * 288 + ks * 32 + quad * 8);
        bf16x8 af1 = *(const bf16x8*)(w2t + ((mtg * 2 + 1) * 16 + nl) * 288 + ks * 32 + quad * 8);
        int ro = r * 9360 + 72 * kx + quad * 16;
#pragma unroll
        for (int ni = 0; ni < 2; ++ni) {
            int x = (ntg * 2 + ni) * 16 + nl;
            union { u64 d[2]; bf16x8 v; } bb;
            bb.d[0] = *(const u64*)(lb + ro + 144 * x);
            bb.d[1] = *(const u64*)(lb + ro + 144 * x + 8);
            acc[0 * 2 + ni] = __builtin_amdgcn_mfma_f32_16x16x32_bf16(af0, bb.v, acc[0 * 2 + ni], 0, 0, 0);
            acc[1 * 2 + ni] = __builtin_amdgcn_mfma_f32_16x16x32_bf16(af1, bb.v, acc[1 * 2 + ni], 0, 0, 0);
        }
    }
#pragma unroll
    for (int ni = 0; ni < 2; ++ni) {
        int x = (ntg * 2 + ni) * 16 + nl;
        if (x < 62) {
#pragma unroll
            for (int mi = 0; mi < 2; ++mi) {
                int oc0 = (mtg * 2 + mi) * 16 + quad * 4;
                f32x4 a = acc[mi * 2 + ni];
                u64 pk = pack4bf(fmaxf(a[0], 0.f), fmaxf(a[1], 0.f), fmaxf(a[2], 0.f), fmaxf(a[3], 0.f));
                *(u64*)(out + (((size_t)b * 46 + y) * 62 + x) * 64 + oc0) = pk;
            }
        }
    }
}

// ---------------- conv3: NHWC in -> NCHW-flatten bf16 [b][64*660]. 3x3 s2.
__global__ __launch_bounds__(256) void k_conv3m(const unsigned short* __restrict__ in,
                                                const unsigned short* __restrict__ w3t,
                                                const float* __restrict__ bias,
                                                unsigned short* __restrict__ out) {
    int b = blockIdx.x, y = blockIdx.y;
    int tid = threadIdx.x;
    __shared__ __align__(16) unsigned short lds[3 * 65 * 68];
    char* lb = (char*)lds;
    const u64* in64 = (const u64*)in;
    size_t gbase = ((size_t)b * 46 + 2 * y) * 62 * 16;
    for (int u = tid; u < 2976; u += 256) {
        int r = u / 992, rem = u - r * 992;
        int p = rem >> 4, h = rem & 15;
        u64 v = in64[gbase + (size_t)r * 62 * 16 + p * 16 + h];
        *(u64*)(lb + r * 8840 + p * 136 + h * 8) = v;
    }
    __syncthreads();
    int wave = tid >> 6, lane = tid & 63;
    int quad = lane >> 4, nl = lane & 15;
    int mtg = wave & 1, nt = wave >> 1;
    f32x4 acc[2];
#pragma unroll
    for (int mi = 0; mi < 2; ++mi) {
        float4 bv = *(const float4*)(bias + (mtg * 2 + mi) * 16 + quad * 4);
        acc[mi][0] = bv.x; acc[mi][1] = bv.y; acc[mi][2] = bv.z; acc[mi][3] = bv.w;
    }
    int x = nt * 16 + nl;
#pragma unroll
    for (int ks = 0; ks < 18; ++ks) {
        const int pos = ks >> 1, half = ks & 1;
        const int r = pos / 3, kx = pos - r * 3;
        bf16x8 af0 = *(const bf16x8*)(w3t + ((mtg * 2 + 0) * 16 + nl) * 576 + ks * 32 + quad * 8);
        bf16x8 af1 = *(const bf16x8*)(w3t + ((mtg * 2 + 1) * 16 + nl) * 576 + ks * 32 + quad * 8);
        int ro = r * 8840 + 136 * kx + half * 64 + quad * 16;
        union { u64 d[2]; bf16x8 v; } bb;
        bb.d[0] = *(const u64*)(lb + ro + 272 * x);
        bb.d[1] = *(const u64*)(lb + ro + 272 * x + 8);
        acc[0] = __builtin_amdgcn_mfma_f32_16x16x32_bf16(af0, bb.v, acc[0], 0, 0, 0);
        acc[1] = __builtin_amdgcn_mfma_f32_16x16x32_bf16(af1, bb.v, acc[1], 0, 0, 0);
    }
    if (x < 30) {
#pragma unroll
        for (int mi = 0; mi < 2; ++mi) {
            int oc0 = (mtg * 2 + mi) * 16 + quad * 4;
#pragma unroll
            for (int r2 = 0; r2 < 4; ++r2)
                out[(size_t)b * 42240 + (oc0 + r2) * 660 + y * 30 + x] = f2bf(acc[mi][r2]);
        }
    }
}

// ---------------- fc1 as bf16 MFMA GEMM
__global__ __launch_bounds__(256) void k_fc1_mfma(const unsigned short* __restrict__ A,
                                                  const float* __restrict__ W,
                                                  float* __restrict__ part) {
    int kc = blockIdx.x;
    int nb = blockIdx.y;
    int wave = threadIdx.x >> 6, lane = threadIdx.x & 63;
    int m16 = lane & 15, quad = lane >> 4;
    int n = nb * 64 + wave * 16 + m16;
    const float* wrow = W + (size_t)n * 42240;
    const unsigned short* abase = A + (size_t)m16 * 42240;
    f32x4 acc[8] = {};
    int k0 = kc * 640 + quad * 8;
    for (int ks = 0; ks < 20; ++ks) {
        int k = k0 + ks * 32;
        const uint32_t* wp = (const uint32_t*)(wrow + k);
        uint32_t u0 = wp[0], u1 = wp[1], u2 = wp[2], u3 = wp[3];
        uint32_t u4 = wp[4], u5 = wp[5], u6 = wp[6], u7 = wp[7];
        union { uint32_t u[4]; bf16x8 v; } bf;
        bf.u[0] = (u0 >> 16) | (u1 & 0xffff0000u);
        bf.u[1] = (u2 >> 16) | (u3 & 0xffff0000u);
        bf.u[2] = (u4 >> 16) | (u5 & 0xffff0000u);
        bf.u[3] = (u6 >> 16) | (u7 & 0xffff0000u);
#pragma unroll
        for (int tm = 0; tm < 8; ++tm) {
            bf16x8 af = *(const bf16x8*)(abase + (size_t)tm * 16 * 42240 + k);
            acc[tm] = __builtin_amdgcn_mfma_f32_16x16x32_bf16(af, bf.v, acc[tm], 0, 0, 0);
        }
    }
    float* pb = part + ((size_t)kc * 128) * 256 + n;
#pragma unroll
    for (int tm = 0; tm < 8; ++tm) {
        int row = tm * 16 + quad * 4;
#pragma unroll
        for (int r = 0; r < 4; ++r) pb[(size_t)(row + r) * 256] = acc[tm][r];
    }
}

// ---------------- fc1-combine + fc2 + lowd1 + lowd2 fused -> cnn_out2
__global__ __launch_bounds__(128) void k_head(const float* __restrict__ part,
                                              const float* __restrict__ f1b,
                                              const float* __restrict__ w2, const float* __restrict__ b2,
                                              const float* __restrict__ lw1, const float* __restrict__ lb1,
                                              const float* __restrict__ lw2, const float* __restrict__ lb2,
                                              float* __restrict__ cnn2) {
    int b = blockIdx.x, n = threadIdx.x;
    __shared__ float xa[256];
    __shared__ float xb[128];
    __shared__ float xc[128];
#pragma unroll
    for (int h = 0; h < 2; ++h) {
        int col = n + h * 128;
        float s = f1b[col];
        for (int kc = 0; kc < 66; ++kc) s += part[((size_t)kc * 128 + b) * 256 + col];
        xa[col] = fmaxf(s, 0.f);
    }
    __syncthreads();
    float acc = b2[n];
    for (int k = 0; k < 256; ++k) acc = fmaf(xa[k], w2[n * 256 + k], acc);
    xb[n] = acc;
    __syncthreads();
    acc = lb1[n];
    for (int k = 0; k < 128; ++k) acc = fmaf(xb[k], lw1[n * 128 + k], acc);
    xc[n] = fmaxf(acc, 0.f);
    __syncthreads();
    acc = lb2[n];
    for (int k = 0; k < 128; ++k) acc = fmaf(xc[k], lw2[n * 128 + k], acc);
    cnn2[b * 128 + n] = acc;
}

// ---------------- action MLP
__global__ __launch_bounds__(256) void k_act(const float* __restrict__ ain,
                                             const float* __restrict__ w1, const float* __restrict__ b1,
                                             const float* __restrict__ w2, const float* __restrict__ b2,
                                             float* __restrict__ abuf) {
    int idx = blockIdx.x * 256 + threadIdx.x;
    float x0 = ain[idx * 2], x1 = ain[idx * 2 + 1];
    float h1[16];
#pragma unroll
    for (int i = 0; i < 16; ++i)
        h1[i] = fmaxf(fmaf(x0, w1[i * 2], fmaf(x1, w1[i * 2 + 1], b1[i])), 0.f);
#pragma unroll
    for (int i = 0; i < 16; ++i) {
        float a = b2[i];
#pragma unroll
        for (int j = 0; j < 16; ++j) a = fmaf(h1[j], w2[i * 16 + j], a);
        abuf[idx * 16 + i] = a;
    }
}

// ---------------- LSTM: one wave per sample, wave-synchronous, f16 dot2.
__global__ __launch_bounds__(64, 1) void k_lstm(const float* __restrict__ abuf,
                                                const float* __restrict__ cnn2,
                                                const uint32_t* __restrict__ wpk,
                                                const float* __restrict__ bih,
                                                const float* __restrict__ bhh,
                                                float* __restrict__ lout) {
    int b = blockIdx.x, lane = threadIdx.x;
    uint32_t xpk[8];
#pragma unroll
    for (int t = 0; t < 8; ++t) {
        float x0 = 0.f, x1 = 0.f;
        if (lane < 8) {
            const float* ap = abuf + (b * 8 + t) * 16 + 2 * lane;
            x0 = ap[0];
            x1 = ap[1];
        }
        xpk[t] = pkh2(x0, x1);
    }
    float h0 = cnn2[b * 128 + 64 + lane];
    float c0 = cnn2[b * 128 + lane];
    const uint4* wbase = (const uint4*)wpk;
    for (int l = 0; l < 8; ++l) {
        uint4 wreg[64];
        const uint4* wp = wbase + (size_t)l * 4096 + lane;
#pragma unroll
        for (int j = 0; j < 64; ++j) wreg[j] = wp[j * 64];
        float bias0 = bih[l * 256 + lane] + bhh[l * 256 + lane];
        float bias1 = bih[l * 256 + 64 + lane] + bhh[l * 256 + 64 + lane];
        float bias2 = bih[l * 256 + 128 + lane] + bhh[l * 256 + 128 + lane];
        float bias3 = bih[l * 256 + 192 + lane] + bhh[l * 256 + 192 + lane];
        float h = h0, c = c0;
        uint32_t hpk = packpair(h);
#pragma unroll
        for (int t = 0; t < 8; ++t) {
            float a0 = bias0, a1 = bias1, a2 = bias2, a3 = bias3;
#pragma unroll
            for (int p = 0; p < 32; ++p) {
                uint32_t bx = (uint32_t)__builtin_amdgcn_readlane((int)xpk[t], p);
                int q = p >> 2, e = p & 3;
                a0 = dot2(comp4(wreg[q], e), bx, a0);
                a1 = dot2(comp4(wreg[16 + q], e), bx, a1);
                a2 = dot2(comp4(wreg[32 + q], e), bx, a2);
                a3 = dot2(comp4(wreg[48 + q], e), bx, a3);
            }
#pragma unroll
            for (int m = 0; m < 32; ++m) {
                uint32_t bh = (uint32_t)__builtin_amdgcn_readlane((int)hpk, 2 * m);
                int q = 8 + (m >> 2), e = m & 3;
                a0 = dot2(comp4(wreg[q], e), bh, a0);
                a1 = dot2(comp4(wreg[16 + q], e), bh, a1);
                a2 = dot2(comp4(wreg[32 + q], e), bh, a2);
                a3 = dot2(comp4(wreg[48 + q], e), bh, a3);
            }
            float gi = sigm(a0), gf = sigm(a1), gv = tanh_(a2), go = sigm(a3);
            c = gf * c + gi * gv;
            h = go * tanh_(c);
            hpk = packpair(h);
            xpk[t] = hpk;
            if (l == 7) lout[(b * 8 + t) * 64 + lane] = h;
        }
    }
}

// ---------------- out MLP + rotation -> d_out (128,8,4)
__global__ __launch_bounds__(256) void k_out(const float* __restrict__ lout,
                                             const float* __restrict__ w1, const float* __restrict__ b1,
                                             const float* __restrict__ w2, const float* __restrict__ b2,
                                             const float* __restrict__ gt, float* __restrict__ out) {
    int idx = blockIdx.x * 256 + threadIdx.x;
    int b = idx >> 3;
    float x[64];
#pragma unroll
    for (int j = 0; j < 64; ++j) x[j] = lout[idx * 64 + j];
    float h[32];
#pragma unroll 8
    for (int i = 0; i < 32; ++i) {
        float a = b1[i];
#pragma unroll
        for (int j = 0; j < 64; ++j) a = fmaf(x[j], w1[i * 64 + j], a);
        h[i] = fmaxf(a, 0.f);
    }
    float mo[4];
#pragma unroll
    for (int i = 0; i < 4; ++i) {
        float a = b2[i];
#pragma unroll
        for (int j = 0; j < 32; ++j) a = fmaf(h[j], w2[i * 32 + j], a);
        mo[i] = a;
    }
    float yaw = gt[b * 48 + 5];
    float cy = cosf(yaw), sy = sinf(yaw);
    out[idx * 4 + 0] = fmaf(mo[0], cy, fmaf(mo[1], sy, gt[b * 48 + 1]));
    out[idx * 4 + 1] = fmaf(mo[0], -sy, fmaf(mo[1], cy, gt[b * 48 + 2]));
    out[idx * 4 + 2] = mo[2] + gt[b * 48 + 3];
    out[idx * 4 + 3] = mo[3];
}

extern "C" void kernel_launch(void* const* d_in, const int* in_sizes, int n_in,
                              void* d_out, int out_size, void* d_ws, size_t ws_size,
                              hipStream_t stream) {
    const float* img = (const float*)d_in[0];
    const float* ain = (const float*)d_in[1];
    const float* gt = (const float*)d_in[2];
    const float* c1w = (const float*)d_in[3];
    const float* c1b = (const float*)d_in[4];
    const float* c2w = (const float*)d_in[5];
    const float* c2b = (const float*)d_in[6];
    const float* c3w = (const float*)d_in[7];
    const float* c3b = (const float*)d_in[8];
    const float* f1w = (const float*)d_in[9];
    const float* f1b = (const float*)d_in[10];
    const float* f2w = (const float*)d_in[11];
    const float* f2b = (const float*)d_in[12];
    const float* l1w = (const float*)d_in[13];
    const float* l1b = (const float*)d_in[14];
    const float* l2w = (const float*)d_in[15];
    const float* l2b = (const float*)d_in[16];
    const float* a1w = (const float*)d_in[17];
    const float* a1b = (const float*)d_in[18];
    const float* a2w = (const float*)d_in[19];
    const float* a2b = (const float*)d_in[20];
    const float* wih0 = (const float*)d_in[21];
    const float* wih = (const float*)d_in[22];
    const float* whh = (const float*)d_in[23];
    const float* bihp = (const float*)d_in[24];
    const float* bhhp = (const float*)d_in[25];
    const float* o1w = (const float*)d_in[26];
    const float* o1b = (const float*)d_in[27];
    const float* o2w = (const float*)d_in[28];
    const float* o2b = (const float*)d_in[29];
    float* out = (float*)d_out;

    char* ws = (char*)d_ws;
    unsigned short* c1o = (unsigned short*)(ws);                 // 97,026,048 B
    unsigned short* c2o = (unsigned short*)(ws + 97026048);      // 46,727,168 B
    unsigned short* c3o = (unsigned short*)(ws + 143753216);     // 10,813,440 B
    float* f1p = (float*)(ws + 154566656);                       // 8,650,752 B
    float* cnn2 = (float*)(ws + 163348480);
    float* abuf = (float*)(ws + 163414016);
    float* lo = (float*)(ws + 163479552);
    unsigned short* w1t = (unsigned short*)(ws + 163741696);     // 8,192 B
    unsigned short* w2t = (unsigned short*)(ws + 163749888);     // 36,864 B
    unsigned short* w3t = (unsigned short*)(ws + 163786752);     // 73,728 B
    uint32_t* wpk = (uint32_t*)(ws + 163860480);                 // 524,288 B

    k_wprep<<<232, 256, 0, stream>>>(c1w, c2w, c3w, w1t, w2t, w3t);
    k_wprep_lstm<<<128, 256, 0, stream>>>(wih0, wih, whh, wpk);
    k_conv1m<<<dim3(128, 24), 256, 0, stream>>>(img, w1t, c1b, c1o);
    k_conv2m<<<dim3(128, 46), 256, 0, stream>>>(c1o, w2t, c2b, c2o);
    k_conv3m<<<dim3(128, 22), 256, 0, stream>>>(c2o, w3t, c3b, c3o);
    k_fc1_mfma<<<dim3(66, 4), 256, 0, stream>>>(c3o, f1w, f1p);
    k_head<<<128, 128, 0, stream>>>(f1p, f1b, f2w, f2b, l1w, l1b, l2w, l2b, cnn2);
    k_act<<<4, 256, 0, stream>>>(ain, a1w, a1b, a2w, a2b, abuf);
    k_lstm<<<128, 64, 0, stream>>>(abuf, cnn2, wpk, bihp, bhhp, lo);
    k_out<<<4, 256, 0, stream>>>(lo, o1w, o1b, o2w, o2b, gt, out);
}

// Round 8
// 455.727 us; speedup vs baseline: 3.9739x; 1.0875x over previous
//
#include <hip/hip_runtime.h>
#include <cstdint>

#define DEV __device__ __forceinline__

typedef __attribute__((ext_vector_type(8))) short bf16x8;
typedef __attribute__((ext_vector_type(4))) float f32x4;
typedef __attribute__((ext_vector_type(2))) __fp16 h2t;
typedef unsigned long long u64;

DEV unsigned short f2bf(float f) {
    unsigned u = __float_as_uint(f);
    unsigned r = u + 0x7fffu + ((u >> 16) & 1u);
    return (unsigned short)(r >> 16);
}
DEV uint32_t pkbf2(float a, float b) {
    return (uint32_t)f2bf(a) | ((uint32_t)f2bf(b) << 16);
}
DEV uint32_t pkh2(float a, float b) {
    h2t p = __builtin_amdgcn_cvt_pkrtz(a, b);
    union { h2t h; uint32_t u; } c;
    c.h = p;
    return c.u;
}
DEV float dot2(uint32_t w, uint32_t x, float acc) {
    union { uint32_t u; h2t h; } a, b;
    a.u = w; b.u = x;
    return __builtin_amdgcn_fdot2(a.h, b.h, acc, false);
}
DEV float sigm(float x) { return __builtin_amdgcn_rcpf(1.f + __expf(-x)); }
DEV float tanh_(float x) { return fmaf(2.f, sigm(2.f * x), -1.f); }
DEV uint32_t packpair(float h) {
    float hs = __int_as_float(__builtin_amdgcn_ds_swizzle(__float_as_int(h), 0x041F));
    return pkh2(h, hs);
}
DEV uint32_t comp4(uint4 v, int e) {
    return (e == 0) ? v.x : (e == 1) ? v.y : (e == 2) ? v.z : v.w;
}
DEV u64 pack4bf(float a, float b, float c, float d) {
    unsigned lo = (unsigned)f2bf(a) | ((unsigned)f2bf(b) << 16);
    unsigned hi = (unsigned)f2bf(c) | ((unsigned)f2bf(d) << 16);
    return (u64)lo | ((u64)hi << 32);
}

// ---------------- weight prep (bf16, K-chunk order)
// conv1: w1t[oc][k], k = cc*8 + u*4 + c; chunk cc<15: taps (r=cc/3, kx=2*(cc%3)+u);
//        kx=5 / cc=15 / c=3 are phantom slots with ZERO weight.
// w2t[64][288]: k = tap*32 + c; w3t[64][576]: k = tap*64 + c
__global__ __launch_bounds__(256) void k_wprep(const float* __restrict__ w1,
                                               const float* __restrict__ w2,
                                               const float* __restrict__ w3,
                                               unsigned short* __restrict__ w1t,
                                               unsigned short* __restrict__ w2t,
                                               unsigned short* __restrict__ w3t) {
    int i = blockIdx.x * 256 + threadIdx.x;
    if (i < 32 * 128) {
        int oc = i >> 7, k = i & 127;
        int cc = k >> 3, u = (k >> 2) & 1, c = k & 3;
        int r = cc / 3, kx = 2 * (cc - 3 * r) + u;
        w1t[i] = (cc < 15 && kx < 5 && c < 3) ? f2bf(w1[oc * 75 + c * 25 + r * 5 + kx])
                                              : (unsigned short)0;
    } else if (i < 32 * 128 + 64 * 288) {
        int j = i - 32 * 128;
        int oc = j / 288, k = j - oc * 288;
        int pos = k >> 5, c = k & 31;
        w2t[j] = f2bf(w2[oc * 288 + c * 9 + pos]);
    } else if (i < 32 * 128 + 64 * 288 + 64 * 576) {
        int j = i - 32 * 128 - 64 * 288;
        int oc = j / 576, k = j - oc * 576;
        int pos = k >> 6, c = k & 63;
        w3t[j] = f2bf(w3[oc * 576 + c * 9 + pos]);
    }
}

// ---------------- LSTM weight prep: f16 pairs (see k_lstm)
__global__ __launch_bounds__(256) void k_wprep_lstm(const float* __restrict__ Wih0,
                                                    const float* __restrict__ Wih,
                                                    const float* __restrict__ Whh,
                                                    uint32_t* __restrict__ wpk) {
    int idx = blockIdx.x * 256 + threadIdx.x;  // 0..32767
    int lane = idx & 63;
    int j = (idx >> 6) & 63;
    int l = idx >> 12;
    int g = j >> 4, q = j & 15;
    int r = g * 64 + lane;
    uint32_t ov[4];
#pragma unroll
    for (int e = 0; e < 4; ++e) {
        int p = q * 4 + e;
        float w0, w1;
        if (p < 32) {
            int k0 = 2 * p;
            if (l == 0) {
                w0 = (k0 < 16) ? Wih0[r * 16 + k0] : 0.f;
                w1 = (k0 + 1 < 16) ? Wih0[r * 16 + k0 + 1] : 0.f;
            } else {
                const float* base = Wih + ((size_t)(l - 1) * 256 + r) * 64;
                w0 = base[k0];
                w1 = base[k0 + 1];
            }
        } else {
            int k0 = 2 * (p - 32);
            const float* base = Whh + ((size_t)l * 256 + r) * 64;
            w0 = base[k0];
            w1 = base[k0 + 1];
        }
        ov[e] = pkh2(w0, w1);
    }
    uint4 v;
    v.x = ov[0]; v.y = ov[1]; v.z = ov[2]; v.w = ov[3];
    ((uint4*)wpk)[idx] = v;
}

// ---------------- conv1: 4 output rows/block, wave=row, b128 frags, 2 MFMA per frag.
__global__ __launch_bounds__(256) void k_conv1m(const float* __restrict__ img,
                                                const unsigned short* __restrict__ w1t,
                                                const float* __restrict__ bias,
                                                unsigned short* __restrict__ out) {
    int b = blockIdx.x, y0 = blockIdx.y * 4;
    int tid = threadIdx.x;
    __shared__ __align__(16) unsigned short lds[12 * 1040];
    char* lb = (char*)lds;
    const float* ib = img + (size_t)b * 3 * 192 * 256;
#pragma unroll
    for (int r = 0; r < 12; ++r) {
        if (r < 11) {
            int row = 2 * y0 + r;
            if (row > 191) row = 191;
            const float* ip = ib + row * 256 + tid;
            float f0 = ip[0], f1 = ip[192 * 256], f2 = ip[2 * 192 * 256];
            uint32_t lo = (uint32_t)f2bf(f0) | ((uint32_t)f2bf(f1) << 16);
            *(u64*)(lb + r * 2080 + tid * 8) = (u64)lo | ((u64)f2bf(f2) << 32);
        } else {
            *(u64*)(lb + 11 * 2080 + tid * 8) = 0ull;
        }
    }
    __syncthreads();
    int wave = tid >> 6, lane = tid & 63;
    int quad = lane >> 4, nl = lane & 15;
    int ly = wave;
    float4 bv0 = *(const float4*)(bias + quad * 4);
    float4 bv1 = *(const float4*)(bias + 16 + quad * 4);
    f32x4 acc[8][2];
#pragma unroll
    for (int nt = 0; nt < 8; ++nt) {
        acc[nt][0][0] = bv0.x; acc[nt][0][1] = bv0.y; acc[nt][0][2] = bv0.z; acc[nt][0][3] = bv0.w;
        acc[nt][1][0] = bv1.x; acc[nt][1][1] = bv1.y; acc[nt][1][2] = bv1.z; acc[nt][1][3] = bv1.w;
    }
#pragma unroll
    for (int ks = 0; ks < 4; ++ks) {
        int cc = ks * 4 + quad;
        int r = cc / 3, kxp = cc - 3 * r;
        int rb = (2 * ly + r) * 2080 + kxp * 16 + nl * 16;
        bf16x8 af0 = *(const bf16x8*)(w1t + (nl) * 128 + ks * 32 + quad * 8);
        bf16x8 af1 = *(const bf16x8*)(w1t + (16 + nl) * 128 + ks * 32 + quad * 8);
#pragma unroll
        for (int nt = 0; nt < 8; ++nt) {
            bf16x8 bv = *(const bf16x8*)(lb + rb + nt * 256);
            acc[nt][0] = __builtin_amdgcn_mfma_f32_16x16x32_bf16(af0, bv, acc[nt][0], 0, 0, 0);
            acc[nt][1] = __builtin_amdgcn_mfma_f32_16x16x32_bf16(af1, bv, acc[nt][1], 0, 0, 0);
        }
    }
    int y = y0 + ly;
    if (y < 94) {
#pragma unroll
        for (int nt = 0; nt < 8; ++nt) {
            int x = nt * 16 + nl;
            if (x < 126) {
#pragma unroll
                for (int mi = 0; mi < 2; ++mi) {
                    f32x4 a = acc[nt][mi];
                    u64 pk = pack4bf(fmaxf(a[0], 0.f), fmaxf(a[1], 0.f),
                                     fmaxf(a[2], 0.f), fmaxf(a[3], 0.f));
                    *(u64*)(out + (((size_t)b * 94 + y) * 126 + x) * 32 + mi * 16 + quad * 4) = pk;
                }
            }
        }
    }
}

// ---------------- conv2: NHWC in -> NHWC out [128][46][62][64]. 3x3 s2 ReLU.
__global__ __launch_bounds__(256) void k_conv2m(const unsigned short* __restrict__ in,
                                                const unsigned short* __restrict__ w2t,
                                                const float* __restrict__ bias,
                                                unsigned short* __restrict__ out) {
    int b = blockIdx.x, y = blockIdx.y;
    int tid = threadIdx.x;
    __shared__ __align__(16) unsigned short lds[3 * 130 * 36];
    char* lb = (char*)lds;
    const u64* in64 = (const u64*)in;
    size_t gbase = ((size_t)b * 94 + 2 * y) * 126 * 8;
    for (int u = tid; u < 3024; u += 256) {
        int r = u / 1008, rem = u - r * 1008;
        int p = rem >> 3, h = rem & 7;
        u64 v = in64[gbase + (size_t)r * 126 * 8 + p * 8 + h];
        *(u64*)(lb + r * 9360 + p * 72 + h * 8) = v;
    }
    __syncthreads();
    int wave = tid >> 6, lane = tid & 63;
    int quad = lane >> 4, nl = lane & 15;
    int mtg = wave & 1, ntg = wave >> 1;
    f32x4 acc[4];
#pragma unroll
    for (int mi = 0; mi < 2; ++mi) {
        float4 bv = *(const float4*)(bias + (mtg * 2 + mi) * 16 + quad * 4);
#pragma unroll
        for (int ni = 0; ni < 2; ++ni) {
            acc[mi * 2 + ni][0] = bv.x; acc[mi * 2 + ni][1] = bv.y;
            acc[mi * 2 + ni][2] = bv.z; acc[mi * 2 + ni][3] = bv.w;
        }
    }
#pragma unroll
    for (int ks = 0; ks < 9; ++ks) {
        const int r = ks / 3, kx = ks - r * 3;
        bf16x8 af0 = *(const bf16x8*)(w2t + ((mtg * 2 + 0) * 16 + nl) * 288 + ks * 32 + quad * 8);
        bf16x8 af1 = *(const bf16x8*)(w2t + ((mtg * 2 + 1) * 16 + nl) * 288 + ks * 32 + quad * 8);
        int ro = r * 9360 + 72 * kx + quad * 16;
#pragma unroll
        for (int ni = 0; ni < 2; ++ni) {
            int x = (ntg * 2 + ni) * 16 + nl;
            union { u64 d[2]; bf16x8 v; } bb;
            bb.d[0] = *(const u64*)(lb + ro + 144 * x);
            bb.d[1] = *(const u64*)(lb + ro + 144 * x + 8);
            acc[0 * 2 + ni] = __builtin_amdgcn_mfma_f32_16x16x32_bf16(af0, bb.v, acc[0 * 2 + ni], 0, 0, 0);
            acc[1 * 2 + ni] = __builtin_amdgcn_mfma_f32_16x16x32_bf16(af1, bb.v, acc[1 * 2 + ni], 0, 0, 0);
        }
    }
#pragma unroll
    for (int ni = 0; ni < 2; ++ni) {
        int x = (ntg * 2 + ni) * 16 + nl;
        if (x < 62) {
#pragma unroll
            for (int mi = 0; mi < 2; ++mi) {
                int oc0 = (mtg * 2 + mi) * 16 + quad * 4;
                f32x4 a = acc[mi * 2 + ni];
                u64 pk = pack4bf(fmaxf(a[0], 0.f), fmaxf(a[1], 0.f), fmaxf(a[2], 0.f), fmaxf(a[3], 0.f));
                *(u64*)(out + (((size_t)b * 46 + y) * 62 + x) * 64 + oc0) = pk;
            }
        }
    }
}

// ---------------- conv3: NHWC in -> NCHW-flatten bf16 [b][64*660]. 3x3 s2.
__global__ __launch_bounds__(256) void k_conv3m(const unsigned short* __restrict__ in,
                                                const unsigned short* __restrict__ w3t,
                                                const float* __restrict__ bias,
                                                unsigned short* __restrict__ out) {
    int b = blockIdx.x, y = blockIdx.y;
    int tid = threadIdx.x;
    __shared__ __align__(16) unsigned short lds[3 * 65 * 68];
    char* lb = (char*)lds;
    const u64* in64 = (const u64*)in;
    size_t gbase = ((size_t)b * 46 + 2 * y) * 62 * 16;
    for (int u = tid; u < 2976; u += 256) {
        int r = u / 992, rem = u - r * 992;
        int p = rem >> 4, h = rem & 15;
        u64 v = in64[gbase + (size_t)r * 62 * 16 + p * 16 + h];
        *(u64*)(lb + r * 8840 + p * 136 + h * 8) = v;
    }
    __syncthreads();
    int wave = tid >> 6, lane = tid & 63;
    int quad = lane >> 4, nl = lane & 15;
    int mtg = wave & 1, nt = wave >> 1;
    f32x4 acc[2];
#pragma unroll
    for (int mi = 0; mi < 2; ++mi) {
        float4 bv = *(const float4*)(bias + (mtg * 2 + mi) * 16 + quad * 4);
        acc[mi][0] = bv.x; acc[mi][1] = bv.y; acc[mi][2] = bv.z; acc[mi][3] = bv.w;
    }
    int x = nt * 16 + nl;
#pragma unroll
    for (int ks = 0; ks < 18; ++ks) {
        const int pos = ks >> 1, half = ks & 1;
        const int r = pos / 3, kx = pos - r * 3;
        bf16x8 af0 = *(const bf16x8*)(w3t + ((mtg * 2 + 0) * 16 + nl) * 576 + ks * 32 + quad * 8);
        bf16x8 af1 = *(const bf16x8*)(w3t + ((mtg * 2 + 1) * 16 + nl) * 576 + ks * 32 + quad * 8);
        int ro = r * 8840 + 136 * kx + half * 64 + quad * 16;
        union { u64 d[2]; bf16x8 v; } bb;
        bb.d[0] = *(const u64*)(lb + ro + 272 * x);
        bb.d[1] = *(const u64*)(lb + ro + 272 * x + 8);
        acc[0] = __builtin_amdgcn_mfma_f32_16x16x32_bf16(af0, bb.v, acc[0], 0, 0, 0);
        acc[1] = __builtin_amdgcn_mfma_f32_16x16x32_bf16(af1, bb.v, acc[1], 0, 0, 0);
    }
    if (x < 30) {
#pragma unroll
        for (int mi = 0; mi < 2; ++mi) {
            int oc0 = (mtg * 2 + mi) * 16 + quad * 4;
#pragma unroll
            for (int r2 = 0; r2 < 4; ++r2)
                out[(size_t)b * 42240 + (oc0 + r2) * 660 + y * 30 + x] = f2bf(acc[mi][r2]);
        }
    }
}

// ---------------- fc1 v2: LDS-staged double-buffered bf16 MFMA GEMM.
// C(128,256) = A(128,42240)bf16 @ W(256,42240)^T fp32. Grid (kc 0..59, nb 0..3),
// 22 k32-chunks per kc. Coalesced staging; fragments via aligned ds_read_b128.
__global__ __launch_bounds__(256) void k_fc1_mfma(const unsigned short* __restrict__ A,
                                                  const float* __restrict__ W,
                                                  float* __restrict__ part) {
    int kc = blockIdx.x;  // 0..59, 704 K each
    int nb = blockIdx.y;  // 0..3
    int tid = threadIdx.x;
    int wave = tid >> 6, lane = tid & 63;
    int m16 = lane & 15, quad = lane >> 4;
    __shared__ __align__(16) char lw[2][64 * 80];    // W: 64 rows x 32 bf16, stride 80
    __shared__ __align__(16) char la[2][128 * 80];   // A: 128 rows x 32 bf16, stride 80
    int k0 = kc * 704;
    int wrow = tid >> 2, wseg = tid & 3;   // 4 thr/row x 8 fp32
    const float* wsrc = W + (size_t)(nb * 64 + wrow) * 42240 + k0 + wseg * 8;
    int arow = tid >> 1, aseg = tid & 1;   // 2 thr/row x 16 bf16
    const uint4* asrc = (const uint4*)(A + (size_t)arow * 42240 + k0) + aseg * 2;
    float4 wr0 = ((const float4*)wsrc)[0];
    float4 wr1 = ((const float4*)wsrc)[1];
    uint4 ar0 = asrc[0];
    uint4 ar1 = asrc[1];
    f32x4 acc[8] = {};
    char* lwf = nullptr;
    for (int ks = 0; ks < 22; ++ks) {
        int buf = ks & 1;
        uint4 wp;
        wp.x = pkbf2(wr0.x, wr0.y); wp.y = pkbf2(wr0.z, wr0.w);
        wp.z = pkbf2(wr1.x, wr1.y); wp.w = pkbf2(wr1.z, wr1.w);
        *(uint4*)(lw[buf] + wrow * 80 + wseg * 16) = wp;
        *(uint4*)(la[buf] + arow * 80 + aseg * 32) = ar0;
        *(uint4*)(la[buf] + arow * 80 + aseg * 32 + 16) = ar1;
        if (ks < 21) {
            wsrc += 32;
            asrc += 4;
            wr0 = ((const float4*)wsrc)[0];
            wr1 = ((const float4*)wsrc)[1];
            ar0 = asrc[0];
            ar1 = asrc[1];
        }
        __syncthreads();
        bf16x8 wf = *(const bf16x8*)(lw[buf] + (wave * 16 + m16) * 80 + quad * 16);
        const char* lab = la[buf] + m16 * 80 + quad * 16;
#pragma unroll
        for (int tm = 0; tm < 8; ++tm) {
            bf16x8 af = *(const bf16x8*)(lab + tm * 16 * 80);
            acc[tm] = __builtin_amdgcn_mfma_f32_16x16x32_bf16(af, wf, acc[tm], 0, 0, 0);
        }
        (void)lwf;
    }
    int n = nb * 64 + wave * 16 + m16;
    float* pb = part + ((size_t)kc * 128) * 256 + n;
#pragma unroll
    for (int tm = 0; tm < 8; ++tm) {
        int row = tm * 16 + quad * 4;
#pragma unroll
        for (int r = 0; r < 4; ++r) pb[(size_t)(row + r) * 256] = acc[tm][r];
    }
}

// ---------------- fc1-combine + fc2 + lowd1 + lowd2 fused -> cnn_out2
__global__ __launch_bounds__(128) void k_head(const float* __restrict__ part,
                                              const float* __restrict__ f1b,
                                              const float* __restrict__ w2, const float* __restrict__ b2,
                                              const float* __restrict__ lw1, const float* __restrict__ lb1,
                                              const float* __restrict__ lw2, const float* __restrict__ lb2,
                                              float* __restrict__ cnn2) {
    int b = blockIdx.x, n = threadIdx.x;
    __shared__ float xa[256];
    __shared__ float xb[128];
    __shared__ float xc[128];
#pragma unroll
    for (int h = 0; h < 2; ++h) {
        int col = n + h * 128;
        float s = f1b[col];
        for (int kc = 0; kc < 60; ++kc) s += part[((size_t)kc * 128 + b) * 256 + col];
        xa[col] = fmaxf(s, 0.f);
    }
    __syncthreads();
    float acc = b2[n];
    for (int k = 0; k < 256; ++k) acc = fmaf(xa[k], w2[n * 256 + k], acc);
    xb[n] = acc;
    __syncthreads();
    acc = lb1[n];
    for (int k = 0; k < 128; ++k) acc = fmaf(xb[k], lw1[n * 128 + k], acc);
    xc[n] = fmaxf(acc, 0.f);
    __syncthreads();
    acc = lb2[n];
    for (int k = 0; k < 128; ++k) acc = fmaf(xc[k], lw2[n * 128 + k], acc);
    cnn2[b * 128 + n] = acc;
}

// ---------------- action MLP
__global__ __launch_bounds__(256) void k_act(const float* __restrict__ ain,
                                             const float* __restrict__ w1, const float* __restrict__ b1,
                                             const float* __restrict__ w2, const float* __restrict__ b2,
                                             float* __restrict__ abuf) {
    int idx = blockIdx.x * 256 + threadIdx.x;
    float x0 = ain[idx * 2], x1 = ain[idx * 2 + 1];
    float h1[16];
#pragma unroll
    for (int i = 0; i < 16; ++i)
        h1[i] = fmaxf(fmaf(x0, w1[i * 2], fmaf(x1, w1[i * 2 + 1], b1[i])), 0.f);
#pragma unroll
    for (int i = 0; i < 16; ++i) {
        float a = b2[i];
#pragma unroll
        for (int j = 0; j < 16; ++j) a = fmaf(h1[j], w2[i * 16 + j], a);
        abuf[idx * 16 + i] = a;
    }
}

// ---------------- LSTM: one wave per sample, wave-synchronous, f16 dot2.
__global__ __launch_bounds__(64, 1) void k_lstm(const float* __restrict__ abuf,
                                                const float* __restrict__ cnn2,
                                                const uint32_t* __restrict__ wpk,
                                                const float* __restrict__ bih,
                                                const float* __restrict__ bhh,
                                                float* __restrict__ lout) {
    int b = blockIdx.x, lane = threadIdx.x;
    uint32_t xpk[8];
#pragma unroll
    for (int t = 0; t < 8; ++t) {
        float x0 = 0.f, x1 = 0.f;
        if (lane < 8) {
            const float* ap = abuf + (b * 8 + t) * 16 + 2 * lane;
            x0 = ap[0];
            x1 = ap[1];
        }
        xpk[t] = pkh2(x0, x1);
    }
    float h0 = cnn2[b * 128 + 64 + lane];
    float c0 = cnn2[b * 128 + lane];
    const uint4* wbase = (const uint4*)wpk;
    for (int l = 0; l < 8; ++l) {
        uint4 wreg[64];
        const uint4* wp = wbase + (size_t)l * 4096 + lane;
#pragma unroll
        for (int j = 0; j < 64; ++j) wreg[j] = wp[j * 64];
        float bias0 = bih[l * 256 + lane] + bhh[l * 256 + lane];
        float bias1 = bih[l * 256 + 64 + lane] + bhh[l * 256 + 64 + lane];
        float bias2 = bih[l * 256 + 128 + lane] + bhh[l * 256 + 128 + lane];
        float bias3 = bih[l * 256 + 192 + lane] + bhh[l * 256 + 192 + lane];
        float h = h0, c = c0;
        uint32_t hpk = packpair(h);
#pragma unroll
        for (int t = 0; t < 8; ++t) {
            float a0 = bias0, a1 = bias1, a2 = bias2, a3 = bias3;
#pragma unroll
            for (int p = 0; p < 32; ++p) {
                uint32_t bx = (uint32_t)__builtin_amdgcn_readlane((int)xpk[t], p);
                int q = p >> 2, e = p & 3;
                a0 = dot2(comp4(wreg[q], e), bx, a0);
                a1 = dot2(comp4(wreg[16 + q], e), bx, a1);
                a2 = dot2(comp4(wreg[32 + q], e), bx, a2);
                a3 = dot2(comp4(wreg[48 + q], e), bx, a3);
            }
#pragma unroll
            for (int m = 0; m < 32; ++m) {
                uint32_t bh = (uint32_t)__builtin_amdgcn_readlane((int)hpk, 2 * m);
                int q = 8 + (m >> 2), e = m & 3;
                a0 = dot2(comp4(wreg[q], e), bh, a0);
                a1 = dot2(comp4(wreg[16 + q], e), bh, a1);
                a2 = dot2(comp4(wreg[32 + q], e), bh, a2);
                a3 = dot2(comp4(wreg[48 + q], e), bh, a3);
            }
            float gi = sigm(a0), gf = sigm(a1), gv = tanh_(a2), go = sigm(a3);
            c = gf * c + gi * gv;
            h = go * tanh_(c);
            hpk = packpair(h);
            xpk[t] = hpk;
            if (l == 7) lout[(b * 8 + t) * 64 + lane] = h;
        }
    }
}

// ---------------- out MLP + rotation -> d_out (128,8,4)
__global__ __launch_bounds__(256) void k_out(const float* __restrict__ lout,
                                             const float* __restrict__ w1, const float* __restrict__ b1,
                                             const float* __restrict__ w2, const float* __restrict__ b2,
                                             const float* __restrict__ gt, float* __restrict__ out) {
    int idx = blockIdx.x * 256 + threadIdx.x;
    int b = idx >> 3;
    float x[64];
#pragma unroll
    for (int j = 0; j < 64; ++j) x[j] = lout[idx * 64 + j];
    float h[32];
#pragma unroll 8
    for (int i = 0; i < 32; ++i) {
        float a = b1[i];
#pragma unroll
        for (int j = 0; j < 64; ++j) a = fmaf(x[j], w1[i * 64 + j], a);
        h[i] = fmaxf(a, 0.f);
    }
    float mo[4];
#pragma unroll
    for (int i = 0; i < 4; ++i) {
        float a = b2[i];
#pragma unroll
        for (int j = 0; j < 32; ++j) a = fmaf(h[j], w2[i * 32 + j], a);
        mo[i] = a;
    }
    float yaw = gt[b * 48 + 5];
    float cy = cosf(yaw), sy = sinf(yaw);
    out[idx * 4 + 0] = fmaf(mo[0], cy, fmaf(mo[1], sy, gt[b * 48 + 1]));
    out[idx * 4 + 1] = fmaf(mo[0], -sy, fmaf(mo[1], cy, gt[b * 48 + 2]));
    out[idx * 4 + 2] = mo[2] + gt[b * 48 + 3];
    out[idx * 4 + 3] = mo[3];
}

extern "C" void kernel_launch(void* const* d_in, const int* in_sizes, int n_in,
                              void* d_out, int out_size, void* d_ws, size_t ws_size,
                              hipStream_t stream) {
    const float* img = (const float*)d_in[0];
    const float* ain = (const float*)d_in[1];
    const float* gt = (const float*)d_in[2];
    const float* c1w = (const float*)d_in[3];
    const float* c1b = (const float*)d_in[4];
    const float* c2w = (const float*)d_in[5];
    const float* c2b = (const float*)d_in[6];
    const float* c3w = (const float*)d_in[7];
    const float* c3b = (const float*)d_in[8];
    const float* f1w = (const float*)d_in[9];
    const float* f1b = (const float*)d_in[10];
    const float* f2w = (const float*)d_in[11];
    const float* f2b = (const float*)d_in[12];
    const float* l1w = (const float*)d_in[13];
    const float* l1b = (const float*)d_in[14];
    const float* l2w = (const float*)d_in[15];
    const float* l2b = (const float*)d_in[16];
    const float* a1w = (const float*)d_in[17];
    const float* a1b = (const float*)d_in[18];
    const float* a2w = (const float*)d_in[19];
    const float* a2b = (const float*)d_in[20];
    const float* wih0 = (const float*)d_in[21];
    const float* wih = (const float*)d_in[22];
    const float* whh = (const float*)d_in[23];
    const float* bihp = (const float*)d_in[24];
    const float* bhhp = (const float*)d_in[25];
    const float* o1w = (const float*)d_in[26];
    const float* o1b = (const float*)d_in[27];
    const float* o2w = (const float*)d_in[28];
    const float* o2b = (const float*)d_in[29];
    float* out = (float*)d_out;

    char* ws = (char*)d_ws;
    unsigned short* c1o = (unsigned short*)(ws);                 // 97,026,048 B
    unsigned short* c2o = (unsigned short*)(ws + 97026048);      // 46,727,168 B
    unsigned short* c3o = (unsigned short*)(ws + 143753216);     // 10,813,440 B
    float* f1p = (float*)(ws + 154566656);                       // 60*128*256*4 = 7,864,320 B
    float* cnn2 = (float*)(ws + 163348480);
    float* abuf = (float*)(ws + 163414016);
    float* lo = (float*)(ws + 163479552);
    unsigned short* w1t = (unsigned short*)(ws + 163741696);     // 8,192 B
    unsigned short* w2t = (unsigned short*)(ws + 163749888);     // 36,864 B
    unsigned short* w3t = (unsigned short*)(ws + 163786752);     // 73,728 B
    uint32_t* wpk = (uint32_t*)(ws + 163860480);                 // 524,288 B

    k_wprep<<<232, 256, 0, stream>>>(c1w, c2w, c3w, w1t, w2t, w3t);
    k_wprep_lstm<<<128, 256, 0, stream>>>(wih0, wih, whh, wpk);
    k_conv1m<<<dim3(128, 24), 256, 0, stream>>>(img, w1t, c1b, c1o);
    k_conv2m<<<dim3(128, 46), 256, 0, stream>>>(c1o, w2t, c2b, c2o);
    k_conv3m<<<dim3(128, 22), 256, 0, stream>>>(c2o, w3t, c3b, c3o);
    k_fc1_mfma<<<dim3(60, 4), 256, 0, stream>>>(c3o, f1w, f1p);
    k_head<<<128, 128, 0, stream>>>(f1p, f1b, f2w, f2b, l1w, l1b, l2w, l2b, cnn2);
    k_act<<<4, 256, 0, stream>>>(ain, a1w, a1b, a2w, a2b, abuf);
    k_lstm<<<128, 64, 0, stream>>>(abuf, cnn2, wpk, bihp, bhhp, lo);
    k_out<<<4, 256, 0, stream>>>(lo, o1w, o1b, o2w, o2b, gt, out);
}